// Round 1
// 740.676 us; speedup vs baseline: 1.0200x; 1.0200x over previous
//
#include <hip/hip_runtime.h>
#include <stdint.h>

#define B_   8
#define C_   1024
#define HW_  4096
#define K_   64
#define NPIX (B_*HW_)
#define SLAB ((size_t)B_*K_*C_)

typedef __attribute__((ext_vector_type(8))) short short8;
typedef __attribute__((ext_vector_type(4))) float f32x4;

__device__ __forceinline__ uint16_t f2bf(float f) {
  uint32_t u = __float_as_uint(f);
  u += 0x7fffu + ((u >> 16) & 1u);   // round-to-nearest-even
  return (uint16_t)(u >> 16);
}

// async global -> LDS, 16B per lane. LDS dest must be wave-uniform base; lane deposits at base+lane*16.
__device__ __forceinline__ void gl2lds16(const uint16_t* g, uint16_t* l) {
  __builtin_amdgcn_global_load_lds(
      (const __attribute__((address_space(1))) unsigned int*)(g),
      (__attribute__((address_space(3))) unsigned int*)(l), 16, 0, 0);
}

// ---------- prep: normalized centroids, transposed gT[c][n] ----------
__global__ void prep_gT(const float* __restrict__ g, float* __restrict__ gT) {
  int n = blockIdx.x;            // 64 blocks
  int t = threadIdx.x;           // 256 threads
  float vals[4]; float ss = 0.f;
  #pragma unroll
  for (int i = 0; i < 4; i++) { float v = g[n*C_ + t + i*256]; vals[i] = v; ss += v*v; }
  __shared__ float red[256];
  red[t] = ss; __syncthreads();
  for (int s = 128; s > 0; s >>= 1) { if (t < s) red[t] += red[t+s]; __syncthreads(); }
  float scale = 1.f / fmaxf(sqrtf(red[0]), 1e-12f);
  #pragma unroll
  for (int i = 0; i < 4; i++) gT[(t + i*256)*K_ + n] = vals[i]*scale;
}

// ---------- prep: fc_weight fp32 -> bf16 row-major [o][c], 4 elems/thread ----------
__global__ void prep_wb(const float* __restrict__ w, uint16_t* __restrict__ wb) {
  int i = blockIdx.x*256 + threadIdx.x;   // 1024 blocks
  float4 v = *(const float4*)&w[i*4];
  uint16_t o[4] = {f2bf(v.x), f2bf(v.y), f2bf(v.z), f2bf(v.w)};
  *(uint64_t*)&wb[i*4] = *(const uint64_t*)o;
}

// ---------- pass A: argmax_n (x . g_n), fp32, + counts ----------
__launch_bounds__(256)
__global__ void pass_assign(const float* __restrict__ x, const float* __restrict__ gT,
                            int* __restrict__ idx, int* __restrict__ count) {
  int bb = blockIdx.x >> 6;      // grid 512 = 8 b * 64 ptiles
  int pt = blockIdx.x & 63;
  int t = threadIdx.x;
  int lane = t & 63;
  int ng = __builtin_amdgcn_readfirstlane(t >> 6);  // wave id = n-group (uniform -> s_loads of g)
  const float* xp = x + (size_t)bb*C_*HW_ + pt*64 + lane;
  const float* gp = gT + ng*16;
  float acc[16];
  #pragma unroll
  for (int n = 0; n < 16; n++) acc[n] = 0.f;
  for (int c = 0; c < C_; c++) {
    float xv = xp[(size_t)c*HW_];
    const float* gr = gp + c*K_;     // 16 consecutive floats, wave-uniform -> s_load
    #pragma unroll
    for (int n = 0; n < 16; n++) acc[n] = fmaf(xv, gr[n], acc[n]);
  }
  float best = acc[0]; int bi = 0;
  #pragma unroll
  for (int n = 1; n < 16; n++) { if (acc[n] > best) { best = acc[n]; bi = n; } }
  __shared__ float bv[4][64];
  __shared__ int   bn[4][64];
  __shared__ int   hist[64];
  if (t < 64) hist[t] = 0;
  bv[ng][lane] = best; bn[ng][lane] = ng*16 + bi;
  __syncthreads();
  if (t < 64) {
    float mv = bv[0][t]; int mn = bn[0][t];
    #pragma unroll
    for (int wv2 = 1; wv2 < 4; wv2++) { if (bv[wv2][t] > mv) { mv = bv[wv2][t]; mn = bn[wv2][t]; } }
    idx[bb*HW_ + pt*64 + t] = mn;
    atomicAdd(&hist[mn], 1);
  }
  __syncthreads();
  if (t < 64 && hist[t] > 0) atomicAdd(&count[bb*K_ + t], hist[t]);
}

// ---------- pass B: sum_x[b,n,c] partials via LDS bins ----------
// grid 1024 = 8 b * 32 cchunks * 4 pixel-segments -> 3 blocks/CU resident (LDS-capped),
// 12 waves/CU. Global loads for chunk pc+1 prefetched into registers while chunk pc's
// LDS atomics run. Skewed lane->c ordering kills same-address atomic serialization.
__launch_bounds__(256)
__global__ void pass_bins(const float* __restrict__ x, const int* __restrict__ idx,
                          float* __restrict__ sumxp) {
  int bid = blockIdx.x;
  int ps = bid & 3;              // pixel segment (1024 pixels each)
  int cc = (bid >> 2) & 31;      // c chunk (32 channels)
  int bb = bid >> 7;             // batch
  int t = threadIdx.x;
  int lane = t & 63;
  int w2 = (t >> 6) & 1;         // 2 bin copies, shared by wave pairs
  __shared__ float bins[2][64][33];    // 16.9 KB
  __shared__ float xs[32][256];        // 32 KB staging tile
  for (int i = t; i < 2*64*33; i += 256) ((float*)bins)[i] = 0.f;
  const float* xb = x + (size_t)bb*C_*HW_ + (size_t)cc*32*HW_ + (size_t)ps*1024;
  const int*   ib = idx + bb*HW_ + ps*1024;
  int cbase = (lane & 31) + ((lane >> 5) << 4);   // upper half-wave offset by 16

  // preload chunk 0 into registers (compile-time indexed -> stays in VGPRs)
  float xv[32];
  #pragma unroll
  for (int c = 0; c < 32; c++) xv[c] = xb[(size_t)c*HW_ + t];
  int iv = ib[t];

  for (int pc = 0; pc < 4; pc++) {
    #pragma unroll
    for (int c = 0; c < 32; c++) xs[c][t] = xv[c];
    int iv_cur = iv;
    __syncthreads();             // xs ready (and bins init visible on pc==0)
    if (pc < 3) {                // prefetch next chunk; latency hides under atomics
      #pragma unroll
      for (int c = 0; c < 32; c++) xv[c] = xb[(size_t)c*HW_ + (pc+1)*256 + t];
      iv = ib[(pc+1)*256 + t];
    }
    #pragma unroll 8
    for (int j = 0; j < 32; j++) {
      int c = (cbase + j) & 31;  // lanes sharing iv_cur hit different (addr, bank)
      (void)__hip_atomic_fetch_add(&bins[w2][iv_cur][c], xs[c][t],
                                   __ATOMIC_RELAXED, __HIP_MEMORY_SCOPE_WORKGROUP);
    }
    __syncthreads();             // atomics done before xs overwrite
  }
  for (int i = t; i < 64*32; i += 256) {
    int n = i >> 5, c = i & 31;
    float s = bins[0][n][c] + bins[1][n][c];
    sumxp[(size_t)ps*SLAB + ((size_t)bb*K_ + n)*C_ + cc*32 + c] = s;
  }
}

// ---------- pass B2: c_local, c_localT, ||c||^2 (sums the 4 pixel-segment slabs) ----------
__launch_bounds__(256)
__global__ void pass_cfinal(const float* __restrict__ sumxp, const int* __restrict__ count,
                            float* __restrict__ cl, float* __restrict__ clT,
                            float* __restrict__ cn2) {
  int bb = blockIdx.x >> 6, n = blockIdx.x & 63, t = threadIdx.x;  // grid 512
  float inv = 1.f / fmaxf((float)count[bb*K_ + n], 1.f);
  float ss = 0.f;
  #pragma unroll
  for (int i = 0; i < 4; i++) {
    int c = t + i*256;
    size_t o = ((size_t)bb*K_ + n)*C_ + c;
    float v = (sumxp[o] + sumxp[o + SLAB] + sumxp[o + 2*SLAB] + sumxp[o + 3*SLAB]) * inv;
    cl [((size_t)bb*K_ + n)*C_ + c] = v;
    clT[((size_t)bb*C_ + c)*K_ + n] = v;
    ss += v*v;
  }
  __shared__ float red[256];
  red[t] = ss; __syncthreads();
  for (int s = 128; s > 0; s >>= 1) { if (t < s) red[t] += red[t+s]; __syncthreads(); }
  if (t == 0) cn2[bb*K_ + n] = red[0];
}

// ---------- pass C0: w[p] then x_cal bf16, transposed [pixel][c] ----------
__launch_bounds__(256)
__global__ void pass_xcal(const float* __restrict__ x, const int* __restrict__ idx,
                          const float* __restrict__ cl, const float* __restrict__ clT,
                          const float* __restrict__ cn2, uint16_t* __restrict__ xcal) {
  int bb = blockIdx.x >> 6, pt = blockIdx.x & 63, t = threadIdx.x;  // grid 512: 64-pixel tiles
  int lane = t & 63, cs = t >> 6;
  __shared__ float xT[64][129];
  __shared__ int   widx[64];
  __shared__ float pdot[4][64], pxsq[4][64], wv[64];
  if (t < 64) widx[t] = idx[bb*HW_ + pt*64 + t];
  __syncthreads();
  const float* xb = x + (size_t)bb*C_*HW_ + pt*64;
  // phase 1: direct per-pixel dot; lane = pixel, wave = c-strip. Coalesced x, 256B clT gather rows.
  int myi = widx[lane];
  const float* clb = clT + (size_t)bb*C_*K_ + myi;
  float dp = 0.f, xq = 0.f;
  #pragma unroll 4
  for (int ci = 0; ci < 256; ci++) {
    int c = cs*256 + ci;
    float xv = xb[(size_t)c*HW_ + lane];
    dp = fmaf(xv, clb[(size_t)c*K_], dp);
    xq = fmaf(xv, xv, xq);
  }
  pdot[cs][lane] = dp; pxsq[cs][lane] = xq;
  __syncthreads();
  if (t < 64) {
    float d = pdot[0][t]+pdot[1][t]+pdot[2][t]+pdot[3][t];
    float q = pxsq[0][t]+pxsq[1][t]+pxsq[2][t]+pxsq[3][t];
    float msd = (q - 2.f*d + cn2[bb*K_ + widx[t]]) * (1.f/1024.f);
    wv[t] = expf(-msd);
  }
  __syncthreads();
  // phase 2: transpose-write bf16 [pixel][c] (x tiles re-read; L2-hot from phase 1)
  for (int cc = 0; cc < 8; cc++) {
    #pragma unroll
    for (int i = 0; i < 32; i++) {
      int co = cs*32 + i;
      xT[lane][co] = xb[(size_t)(cc*128 + co)*HW_ + lane];
    }
    __syncthreads();
    #pragma unroll 2
    for (int pp = 0; pp < 16; pp++) {
      int p = pp*4 + cs;
      float wval = wv[p]; int iv = widx[p];
      const float* clr = cl + ((size_t)bb*K_ + iv)*C_ + cc*128;
      size_t obase = ((size_t)(bb*HW_ + pt*64 + p))*C_ + cc*128;
      #pragma unroll
      for (int ci = 0; ci < 2; ci++) {
        int co = ci*64 + lane;
        float xvv = xT[p][co];
        float v = fmaf(wval, clr[co] - xvv, xvv);   // x + w*(c-x)
        xcal[obase + co] = f2bf(v);
      }
    }
    __syncthreads();
  }
}

// ---------- pass C: out = relu(W @ x_cal + bias), bf16 MFMA, one 128x128 tile/block ----------
#define BK 64
__launch_bounds__(256)
__global__ void gemm_out(const uint16_t* __restrict__ wb, const uint16_t* __restrict__ xcal,
                         const float* __restrict__ bias, float* __restrict__ out) {
  // 32 KB total: lw|lx during K-loop, aliased by the 32 KB epilogue transpose buffer after.
  __shared__ alignas(16) uint16_t smem[2*128*BK];
  uint16_t* lw = smem;
  uint16_t* lx = smem + 128*BK;
  float*    ep = (float*)smem;
  int t = threadIdx.x;
  int lane = t & 63;
  int w = t >> 6, wm = w & 1, wn = w >> 1;
  // XCD swizzle: xcd = bid&7; within an XCD, ot fastest -> 8 blocks sharing an xcal
  // tile run consecutively on the SAME XCD (xcal tile + all 8 W tiles stay L2-hot).
  int g  = blockIdx.x & 7;
  int li = blockIdx.x >> 3;
  int ot = li & 7;
  int qt = g*32 + (li >> 3);

  const uint16_t* wsrc = wb   + (size_t)ot*128*C_;
  const uint16_t* xsrc = xcal + (size_t)qt*128*C_;

  const f32x4 fzero = {0.f, 0.f, 0.f, 0.f};
  f32x4 acc[4][4];
  #pragma unroll
  for (int i = 0; i < 4; i++)
    #pragma unroll
    for (int j = 0; j < 4; j++) acc[i][j] = fzero;

  for (int kb = 0; kb < C_/BK; kb++) {
    #pragma unroll
    for (int it = 0; it < 4; it++) {
      int s = t + it*256;              // 1024 slots of 16B per tile
      int r = s >> 3, q = s & 7;
      int qm = q ^ (r & 7);            // inverse swizzle on the global side
      uint16_t* ldw = lw + (size_t)(it*256 + w*64)*8;   // wave-uniform base
      uint16_t* ldx = lx + (size_t)(it*256 + w*64)*8;
      gl2lds16(wsrc + (size_t)r*C_ + kb*BK + qm*8, ldw);
      gl2lds16(xsrc + (size_t)r*C_ + kb*BK + qm*8, ldx);
    }
    __syncthreads();                   // drains vmcnt -> LDS tiles ready
    #pragma unroll
    for (int kk = 0; kk < 2; kk++) {
      short8 af[4], bf[4];
      #pragma unroll
      for (int i = 0; i < 4; i++) {
        int row = wm*64 + i*16 + (lane & 15);
        int q = kk*4 + (lane >> 4);
        af[i] = *(const short8*)&lw[row*BK + (q ^ (row & 7))*8];
      }
      #pragma unroll
      for (int j = 0; j < 4; j++) {
        int row = wn*64 + j*16 + (lane & 15);
        int q = kk*4 + (lane >> 4);
        bf[j] = *(const short8*)&lx[row*BK + (q ^ (row & 7))*8];
      }
      #pragma unroll
      for (int i = 0; i < 4; i++)
        #pragma unroll
        for (int j = 0; j < 4; j++)
          acc[i][j] = __builtin_amdgcn_mfma_f32_16x16x32_bf16(af[i], bf[j], acc[i][j], 0, 0, 0);
    }
    __syncthreads();                   // all reads done before next kb's DMA lands
  }
  // epilogue: LDS transpose (aliases lw/lx -- safe after final barrier) -> float4 row stores
  int col = lane & 15, quad = lane >> 4;
  int bq = (qt*128) >> 12;
  int p0 = (qt*128) & 4095;
  #pragma unroll
  for (int ph = 0; ph < 2; ph++) {
    if (wm == ph) {
      #pragma unroll
      for (int i = 0; i < 4; i++)
        #pragma unroll
        for (int j = 0; j < 4; j++) {
          int p = wn*64 + j*16 + col;
          #pragma unroll
          for (int r = 0; r < 4; r++) {
            int o2 = i*16 + quad*4 + r;   // local o within 64
            ep[o2*128 + (((p >> 2) ^ (o2 & 7)) << 2) + (p & 3)] = acc[i][j][r];
          }
        }
    }
    __syncthreads();
    #pragma unroll
    for (int i2 = 0; i2 < 8; i2++) {
      int s = t + i2*256;
      int ol = s >> 5, pf = s & 31;
      float4 v = *(const float4*)&ep[ol*128 + ((pf ^ (ol & 7)) << 2)];
      int o = ot*128 + ph*64 + ol;
      float bi = bias[o];
      v.x = fmaxf(v.x + bi, 0.f); v.y = fmaxf(v.y + bi, 0.f);
      v.z = fmaxf(v.z + bi, 0.f); v.w = fmaxf(v.w + bi, 0.f);
      *(float4*)&out[(size_t)bq*C_*HW_ + (size_t)o*HW_ + p0 + pf*4] = v;
    }
    __syncthreads();
  }
}

extern "C" void kernel_launch(void* const* d_in, const int* in_sizes, int n_in,
                              void* d_out, int out_size, void* d_ws, size_t ws_size,
                              hipStream_t stream) {
  (void)in_sizes; (void)n_in; (void)out_size; (void)ws_size;
  const float* x    = (const float*)d_in[0];
  const float* cent = (const float*)d_in[1];
  const float* fw   = (const float*)d_in[2];
  const float* fb   = (const float*)d_in[3];
  float* out = (float*)d_out;
  char* ws = (char*)d_ws;
  size_t off = 0;
  float*    gT    = (float*)(ws + off);    off += (size_t)C_*K_*4;        // 256 KB
  int*      idx   = (int*)(ws + off);      off += (size_t)NPIX*4;         // 128 KB
  int*      count = (int*)(ws + off);      off += (size_t)B_*K_*4;        // 2 KB
  float*    sumx  = (float*)(ws + off);    off += (size_t)B_*K_*C_*4;     // 2 MB (unused; keeps offsets identical)
  float*    cl    = (float*)(ws + off);    off += (size_t)B_*K_*C_*4;     // 2 MB
  float*    clT   = (float*)(ws + off);    off += (size_t)B_*C_*K_*4;     // 2 MB
  float*    cn2   = (float*)(ws + off);    off += (size_t)B_*K_*4 + 8;    // 2 KB (+pad->16B)
  uint16_t* wb    = (uint16_t*)(ws + off); off += (size_t)C_*C_*2;        // 2 MB
  uint16_t* xcal  = (uint16_t*)(ws + off); off += (size_t)NPIX*C_*2;      // 64 MB
  (void)sumx;
  // partial-sum slabs (4 x 2 MB) alias the xcal region: dead once pass_cfinal reads them,
  // and pass_xcal only writes xcal afterwards.
  float* sumxp = (float*)xcal;

  hipMemsetAsync(count, 0, (size_t)B_*K_*4, stream);
  prep_gT   <<<64,   256, 0, stream>>>(cent, gT);
  prep_wb   <<<1024, 256, 0, stream>>>(fw, wb);
  pass_assign<<<512, 256, 0, stream>>>(x, gT, idx, count);
  pass_bins <<<1024, 256, 0, stream>>>(x, idx, sumxp);
  pass_cfinal<<<512, 256, 0, stream>>>(sumxp, count, cl, clT, cn2);
  pass_xcal <<<512,  256, 0, stream>>>(x, idx, cl, clT, cn2, xcal);
  gemm_out  <<<2048, 256, 0, stream>>>(wb, xcal, fb, out);
}

// Round 2
// 589.148 us; speedup vs baseline: 1.2824x; 1.2572x over previous
//
#include <hip/hip_runtime.h>
#include <stdint.h>

#define B_   8
#define C_   1024
#define HW_  4096
#define K_   64
#define NPIX (B_*HW_)
#define SLAB ((size_t)B_*K_*C_)
#define NSEG 8

typedef __attribute__((ext_vector_type(8))) short short8;
typedef __attribute__((ext_vector_type(4))) float f32x4;

__device__ __forceinline__ uint16_t f2bf(float f) {
  uint32_t u = __float_as_uint(f);
  u += 0x7fffu + ((u >> 16) & 1u);   // round-to-nearest-even
  return (uint16_t)(u >> 16);
}

// async global -> LDS, 16B per lane. LDS dest must be wave-uniform base; lane deposits at base+lane*16.
__device__ __forceinline__ void gl2lds16(const uint16_t* g, uint16_t* l) {
  __builtin_amdgcn_global_load_lds(
      (const __attribute__((address_space(1))) unsigned int*)(g),
      (__attribute__((address_space(3))) unsigned int*)(l), 16, 0, 0);
}

// ---------- prep: normalized centroids, transposed gT[c][n] ----------
__global__ void prep_gT(const float* __restrict__ g, float* __restrict__ gT) {
  int n = blockIdx.x;            // 64 blocks
  int t = threadIdx.x;           // 256 threads
  float vals[4]; float ss = 0.f;
  #pragma unroll
  for (int i = 0; i < 4; i++) { float v = g[n*C_ + t + i*256]; vals[i] = v; ss += v*v; }
  __shared__ float red[256];
  red[t] = ss; __syncthreads();
  for (int s = 128; s > 0; s >>= 1) { if (t < s) red[t] += red[t+s]; __syncthreads(); }
  float scale = 1.f / fmaxf(sqrtf(red[0]), 1e-12f);
  #pragma unroll
  for (int i = 0; i < 4; i++) gT[(t + i*256)*K_ + n] = vals[i]*scale;
}

// ---------- prep: fc_weight fp32 -> bf16 row-major [o][c], 4 elems/thread ----------
__global__ void prep_wb(const float* __restrict__ w, uint16_t* __restrict__ wb) {
  int i = blockIdx.x*256 + threadIdx.x;   // 1024 blocks
  float4 v = *(const float4*)&w[i*4];
  uint16_t o[4] = {f2bf(v.x), f2bf(v.y), f2bf(v.z), f2bf(v.w)};
  *(uint64_t*)&wb[i*4] = *(const uint64_t*)o;
}

// ---------- pass A: argmax_n (x . g_n), fp32, + counts ----------
__launch_bounds__(256)
__global__ void pass_assign(const float* __restrict__ x, const float* __restrict__ gT,
                            int* __restrict__ idx, int* __restrict__ count) {
  int bb = blockIdx.x >> 6;      // grid 512 = 8 b * 64 ptiles
  int pt = blockIdx.x & 63;
  int t = threadIdx.x;
  int lane = t & 63;
  int ng = __builtin_amdgcn_readfirstlane(t >> 6);  // wave id = n-group (uniform -> s_loads of g)
  const float* xp = x + (size_t)bb*C_*HW_ + pt*64 + lane;
  const float* gp = gT + ng*16;
  float acc[16];
  #pragma unroll
  for (int n = 0; n < 16; n++) acc[n] = 0.f;
  for (int c = 0; c < C_; c++) {
    float xv = xp[(size_t)c*HW_];
    const float* gr = gp + c*K_;     // 16 consecutive floats, wave-uniform -> s_load
    #pragma unroll
    for (int n = 0; n < 16; n++) acc[n] = fmaf(xv, gr[n], acc[n]);
  }
  float best = acc[0]; int bi = 0;
  #pragma unroll
  for (int n = 1; n < 16; n++) { if (acc[n] > best) { best = acc[n]; bi = n; } }
  __shared__ float bv[4][64];
  __shared__ int   bn[4][64];
  __shared__ int   hist[64];
  if (t < 64) hist[t] = 0;
  bv[ng][lane] = best; bn[ng][lane] = ng*16 + bi;
  __syncthreads();
  if (t < 64) {
    float mv = bv[0][t]; int mn = bn[0][t];
    #pragma unroll
    for (int wv2 = 1; wv2 < 4; wv2++) { if (bv[wv2][t] > mv) { mv = bv[wv2][t]; mn = bn[wv2][t]; } }
    idx[bb*HW_ + pt*64 + t] = mn;
    atomicAdd(&hist[mn], 1);
  }
  __syncthreads();
  if (t < 64 && hist[t] > 0) atomicAdd(&count[bb*K_ + t], hist[t]);
}

// ---------- pass B: sum_x[b,n,c] partials as a one-hot bf16 MFMA GEMM ----------
// D[c][n] = sum_p X[c][p] * onehot[p][n]. A-frags come straight from x's [c][p]
// layout (8 consecutive pixels per lane, same fragment convention as gemm_out);
// B one-hot frags are generated IN REGISTERS from idx (2 VALU/elem). No LDS, no
// atomics -- this removes the serialized LDS-atomic RMW chain that capped the
// scatter version at ~184us regardless of occupancy.
// grid 1024 = 8 b * 16 ctiles(64 rows) * 8 psegs(512 pixels).
__launch_bounds__(256)
__global__ void pass_bins(const float* __restrict__ x, const int* __restrict__ idx,
                          float* __restrict__ sumxp) {
  int bid = blockIdx.x;
  int ps = bid & 7;              // pixel segment (512 pixels)
  int ct = (bid >> 3) & 15;      // c tile (64 rows)
  int bb = bid >> 7;             // batch
  int t = threadIdx.x;
  int lane = t & 63;
  int w = t >> 6;                // wave -> 16 c-rows
  int col = lane & 15;
  int kg  = lane >> 4;           // k-group: 8 consecutive pixels per lane
  int crow = ct*64 + w*16 + col;
  const float* xp = x + (size_t)bb*C_*HW_ + (size_t)crow*HW_ + ps*512 + kg*8;
  const int*   ip = idx + bb*HW_ + ps*512 + kg*8;

  const f32x4 fzero = {0.f, 0.f, 0.f, 0.f};
  f32x4 acc[4];
  #pragma unroll
  for (int f = 0; f < 4; f++) acc[f] = fzero;

  for (int ks = 0; ks < 16; ks++) {
    // A: 8 consecutive pixels of this c-row, fp32 -> bf16
    float a0[8];
    *(float4*)&a0[0] = *(const float4*)&xp[ks*32];
    *(float4*)&a0[4] = *(const float4*)&xp[ks*32 + 4];
    short8 af;
    #pragma unroll
    for (int j = 0; j < 8; j++) af[j] = (short)f2bf(a0[j]);
    // cluster ids of those 8 pixels (same 32B broadcast across a 16-lane group)
    int iv8[8];
    *(int4*)&iv8[0] = *(const int4*)&ip[ks*32];
    *(int4*)&iv8[4] = *(const int4*)&ip[ks*32 + 4];
    // 4 one-hot B frags cover n = 0..63 (bf16 1.0 = 0x3F80, exact)
    #pragma unroll
    for (int f = 0; f < 4; f++) {
      int n = f*16 + col;
      short8 bfrag;
      #pragma unroll
      for (int j = 0; j < 8; j++) bfrag[j] = (short)((iv8[j] == n) ? 0x3F80 : 0);
      acc[f] = __builtin_amdgcn_mfma_f32_16x16x32_bf16(af, bfrag, acc[f], 0, 0, 0);
    }
  }
  // C/D layout: col = lane&15 (-> n within frag), row = (lane>>4)*4 + reg (-> c-row)
  #pragma unroll
  for (int f = 0; f < 4; f++) {
    int n = f*16 + col;
    size_t base = (size_t)ps*SLAB + ((size_t)bb*K_ + n)*C_ + ct*64 + w*16 + kg*4;
    *(f32x4*)&sumxp[base] = acc[f];   // 16B aligned; lanes of one n fill a 64B line
  }
}

// ---------- pass B2: c_local, c_localT, ||c||^2 (sums the 8 pixel-segment slabs) ----------
__launch_bounds__(256)
__global__ void pass_cfinal(const float* __restrict__ sumxp, const int* __restrict__ count,
                            float* __restrict__ cl, float* __restrict__ clT,
                            float* __restrict__ cn2) {
  int bb = blockIdx.x >> 6, n = blockIdx.x & 63, t = threadIdx.x;  // grid 512
  float inv = 1.f / fmaxf((float)count[bb*K_ + n], 1.f);
  float ss = 0.f;
  #pragma unroll
  for (int i = 0; i < 4; i++) {
    int c = t + i*256;
    size_t o = ((size_t)bb*K_ + n)*C_ + c;
    float v = 0.f;
    #pragma unroll
    for (int s = 0; s < NSEG; s++) v += sumxp[o + (size_t)s*SLAB];
    v *= inv;
    cl [((size_t)bb*K_ + n)*C_ + c] = v;
    clT[((size_t)bb*C_ + c)*K_ + n] = v;
    ss += v*v;
  }
  __shared__ float red[256];
  red[t] = ss; __syncthreads();
  for (int s = 128; s > 0; s >>= 1) { if (t < s) red[t] += red[t+s]; __syncthreads(); }
  if (t == 0) cn2[bb*K_ + n] = red[0];
}

// ---------- pass C0: w[p] then x_cal bf16, transposed [pixel][c] ----------
__launch_bounds__(256)
__global__ void pass_xcal(const float* __restrict__ x, const int* __restrict__ idx,
                          const float* __restrict__ cl, const float* __restrict__ clT,
                          const float* __restrict__ cn2, uint16_t* __restrict__ xcal) {
  int bb = blockIdx.x >> 6, pt = blockIdx.x & 63, t = threadIdx.x;  // grid 512: 64-pixel tiles
  int lane = t & 63, cs = t >> 6;
  __shared__ float xT[64][129];
  __shared__ int   widx[64];
  __shared__ float pdot[4][64], pxsq[4][64], wv[64];
  if (t < 64) widx[t] = idx[bb*HW_ + pt*64 + t];
  __syncthreads();
  const float* xb = x + (size_t)bb*C_*HW_ + pt*64;
  // phase 1: direct per-pixel dot; lane = pixel, wave = c-strip. Coalesced x, 256B clT gather rows.
  int myi = widx[lane];
  const float* clb = clT + (size_t)bb*C_*K_ + myi;
  float dp = 0.f, xq = 0.f;
  #pragma unroll 4
  for (int ci = 0; ci < 256; ci++) {
    int c = cs*256 + ci;
    float xv = xb[(size_t)c*HW_ + lane];
    dp = fmaf(xv, clb[(size_t)c*K_], dp);
    xq = fmaf(xv, xv, xq);
  }
  pdot[cs][lane] = dp; pxsq[cs][lane] = xq;
  __syncthreads();
  if (t < 64) {
    float d = pdot[0][t]+pdot[1][t]+pdot[2][t]+pdot[3][t];
    float q = pxsq[0][t]+pxsq[1][t]+pxsq[2][t]+pxsq[3][t];
    float msd = (q - 2.f*d + cn2[bb*K_ + widx[t]]) * (1.f/1024.f);
    wv[t] = expf(-msd);
  }
  __syncthreads();
  // phase 2: transpose-write bf16 [pixel][c] (x tiles re-read; L2-hot from phase 1)
  for (int cc = 0; cc < 8; cc++) {
    #pragma unroll
    for (int i = 0; i < 32; i++) {
      int co = cs*32 + i;
      xT[lane][co] = xb[(size_t)(cc*128 + co)*HW_ + lane];
    }
    __syncthreads();
    #pragma unroll 2
    for (int pp = 0; pp < 16; pp++) {
      int p = pp*4 + cs;
      float wval = wv[p]; int iv = widx[p];
      const float* clr = cl + ((size_t)bb*K_ + iv)*C_ + cc*128;
      size_t obase = ((size_t)(bb*HW_ + pt*64 + p))*C_ + cc*128;
      #pragma unroll
      for (int ci = 0; ci < 2; ci++) {
        int co = ci*64 + lane;
        float xvv = xT[p][co];
        float v = fmaf(wval, clr[co] - xvv, xvv);   // x + w*(c-x)
        xcal[obase + co] = f2bf(v);
      }
    }
    __syncthreads();
  }
}

// ---------- pass C: out = relu(W @ x_cal + bias), bf16 MFMA, one 128x128 tile/block ----------
#define BK 64
__launch_bounds__(256)
__global__ void gemm_out(const uint16_t* __restrict__ wb, const uint16_t* __restrict__ xcal,
                         const float* __restrict__ bias, float* __restrict__ out) {
  // 32 KB total: lw|lx during K-loop, aliased by the 32 KB epilogue transpose buffer after.
  __shared__ alignas(16) uint16_t smem[2*128*BK];
  uint16_t* lw = smem;
  uint16_t* lx = smem + 128*BK;
  float*    ep = (float*)smem;
  int t = threadIdx.x;
  int lane = t & 63;
  int w = t >> 6, wm = w & 1, wn = w >> 1;
  // XCD swizzle: xcd = bid&7; within an XCD, ot fastest -> 8 blocks sharing an xcal
  // tile run consecutively on the SAME XCD (xcal tile + all 8 W tiles stay L2-hot).
  int g  = blockIdx.x & 7;
  int li = blockIdx.x >> 3;
  int ot = li & 7;
  int qt = g*32 + (li >> 3);

  const uint16_t* wsrc = wb   + (size_t)ot*128*C_;
  const uint16_t* xsrc = xcal + (size_t)qt*128*C_;

  const f32x4 fzero = {0.f, 0.f, 0.f, 0.f};
  f32x4 acc[4][4];
  #pragma unroll
  for (int i = 0; i < 4; i++)
    #pragma unroll
    for (int j = 0; j < 4; j++) acc[i][j] = fzero;

  for (int kb = 0; kb < C_/BK; kb++) {
    #pragma unroll
    for (int it = 0; it < 4; it++) {
      int s = t + it*256;              // 1024 slots of 16B per tile
      int r = s >> 3, q = s & 7;
      int qm = q ^ (r & 7);            // inverse swizzle on the global side
      uint16_t* ldw = lw + (size_t)(it*256 + w*64)*8;   // wave-uniform base
      uint16_t* ldx = lx + (size_t)(it*256 + w*64)*8;
      gl2lds16(wsrc + (size_t)r*C_ + kb*BK + qm*8, ldw);
      gl2lds16(xsrc + (size_t)r*C_ + kb*BK + qm*8, ldx);
    }
    __syncthreads();                   // drains vmcnt -> LDS tiles ready
    #pragma unroll
    for (int kk = 0; kk < 2; kk++) {
      short8 af[4], bf[4];
      #pragma unroll
      for (int i = 0; i < 4; i++) {
        int row = wm*64 + i*16 + (lane & 15);
        int q = kk*4 + (lane >> 4);
        af[i] = *(const short8*)&lw[row*BK + (q ^ (row & 7))*8];
      }
      #pragma unroll
      for (int j = 0; j < 4; j++) {
        int row = wn*64 + j*16 + (lane & 15);
        int q = kk*4 + (lane >> 4);
        bf[j] = *(const short8*)&lx[row*BK + (q ^ (row & 7))*8];
      }
      #pragma unroll
      for (int i = 0; i < 4; i++)
        #pragma unroll
        for (int j = 0; j < 4; j++)
          acc[i][j] = __builtin_amdgcn_mfma_f32_16x16x32_bf16(af[i], bf[j], acc[i][j], 0, 0, 0);
    }
    __syncthreads();                   // all reads done before next kb's DMA lands
  }
  // epilogue: LDS transpose (aliases lw/lx -- safe after final barrier) -> float4 row stores
  int col = lane & 15, quad = lane >> 4;
  int bq = (qt*128) >> 12;
  int p0 = (qt*128) & 4095;
  #pragma unroll
  for (int ph = 0; ph < 2; ph++) {
    if (wm == ph) {
      #pragma unroll
      for (int i = 0; i < 4; i++)
        #pragma unroll
        for (int j = 0; j < 4; j++) {
          int p = wn*64 + j*16 + col;
          #pragma unroll
          for (int r = 0; r < 4; r++) {
            int o2 = i*16 + quad*4 + r;   // local o within 64
            ep[o2*128 + (((p >> 2) ^ (o2 & 7)) << 2) + (p & 3)] = acc[i][j][r];
          }
        }
    }
    __syncthreads();
    #pragma unroll
    for (int i2 = 0; i2 < 8; i2++) {
      int s = t + i2*256;
      int ol = s >> 5, pf = s & 31;
      float4 v = *(const float4*)&ep[ol*128 + ((pf ^ (ol & 7)) << 2)];
      int o = ot*128 + ph*64 + ol;
      float bi = bias[o];
      v.x = fmaxf(v.x + bi, 0.f); v.y = fmaxf(v.y + bi, 0.f);
      v.z = fmaxf(v.z + bi, 0.f); v.w = fmaxf(v.w + bi, 0.f);
      *(float4*)&out[(size_t)bq*C_*HW_ + (size_t)o*HW_ + p0 + pf*4] = v;
    }
    __syncthreads();
  }
}

extern "C" void kernel_launch(void* const* d_in, const int* in_sizes, int n_in,
                              void* d_out, int out_size, void* d_ws, size_t ws_size,
                              hipStream_t stream) {
  (void)in_sizes; (void)n_in; (void)out_size; (void)ws_size;
  const float* x    = (const float*)d_in[0];
  const float* cent = (const float*)d_in[1];
  const float* fw   = (const float*)d_in[2];
  const float* fb   = (const float*)d_in[3];
  float* out = (float*)d_out;
  char* ws = (char*)d_ws;
  size_t off = 0;
  float*    gT    = (float*)(ws + off);    off += (size_t)C_*K_*4;        // 256 KB
  int*      idx   = (int*)(ws + off);      off += (size_t)NPIX*4;         // 128 KB
  int*      count = (int*)(ws + off);      off += (size_t)B_*K_*4;        // 2 KB
  float*    sumx  = (float*)(ws + off);    off += (size_t)B_*K_*C_*4;     // 2 MB (unused; keeps offsets identical)
  float*    cl    = (float*)(ws + off);    off += (size_t)B_*K_*C_*4;     // 2 MB
  float*    clT   = (float*)(ws + off);    off += (size_t)B_*C_*K_*4;     // 2 MB
  float*    cn2   = (float*)(ws + off);    off += (size_t)B_*K_*4 + 8;    // 2 KB (+pad->16B)
  uint16_t* wb    = (uint16_t*)(ws + off); off += (size_t)C_*C_*2;        // 2 MB
  uint16_t* xcal  = (uint16_t*)(ws + off); off += (size_t)NPIX*C_*2;      // 64 MB
  (void)sumx;
  // partial-sum slabs (8 x 2 MB) alias the xcal region: dead once pass_cfinal reads them,
  // and pass_xcal only writes xcal afterwards.
  float* sumxp = (float*)xcal;

  hipMemsetAsync(count, 0, (size_t)B_*K_*4, stream);
  prep_gT   <<<64,   256, 0, stream>>>(cent, gT);
  prep_wb   <<<1024, 256, 0, stream>>>(fw, wb);
  pass_assign<<<512, 256, 0, stream>>>(x, gT, idx, count);
  pass_bins <<<1024, 256, 0, stream>>>(x, idx, sumxp);
  pass_cfinal<<<512, 256, 0, stream>>>(sumxp, count, cl, clT, cn2);
  pass_xcal <<<512,  256, 0, stream>>>(x, idx, cl, clT, cn2, xcal);
  gemm_out  <<<2048, 256, 0, stream>>>(wb, xcal, fb, out);
}

// Round 3
// 550.074 us; speedup vs baseline: 1.3735x; 1.0710x over previous
//
#include <hip/hip_runtime.h>
#include <stdint.h>

#define B_   8
#define C_   1024
#define HW_  4096
#define K_   64
#define NPIX (B_*HW_)
#define SLAB ((size_t)B_*K_*C_)
#define NSEG 8

typedef __attribute__((ext_vector_type(8))) short short8;
typedef __attribute__((ext_vector_type(4))) float f32x4;

__device__ __forceinline__ uint16_t f2bf(float f) {
  uint32_t u = __float_as_uint(f);
  u += 0x7fffu + ((u >> 16) & 1u);   // round-to-nearest-even
  return (uint16_t)(u >> 16);
}

// async global -> LDS, 16B per lane. LDS dest must be wave-uniform base; lane deposits at base+lane*16.
__device__ __forceinline__ void gl2lds16(const uint16_t* g, uint16_t* l) {
  __builtin_amdgcn_global_load_lds(
      (const __attribute__((address_space(1))) unsigned int*)(g),
      (__attribute__((address_space(3))) unsigned int*)(l), 16, 0, 0);
}

// ---------- prep: normalized centroids, transposed gT[c][n] ----------
__global__ void prep_gT(const float* __restrict__ g, float* __restrict__ gT) {
  int n = blockIdx.x;            // 64 blocks
  int t = threadIdx.x;           // 256 threads
  float vals[4]; float ss = 0.f;
  #pragma unroll
  for (int i = 0; i < 4; i++) { float v = g[n*C_ + t + i*256]; vals[i] = v; ss += v*v; }
  __shared__ float red[256];
  red[t] = ss; __syncthreads();
  for (int s = 128; s > 0; s >>= 1) { if (t < s) red[t] += red[t+s]; __syncthreads(); }
  float scale = 1.f / fmaxf(sqrtf(red[0]), 1e-12f);
  #pragma unroll
  for (int i = 0; i < 4; i++) gT[(t + i*256)*K_ + n] = vals[i]*scale;
}

// ---------- prep: fc_weight fp32 -> bf16 row-major [o][c], 4 elems/thread ----------
__global__ void prep_wb(const float* __restrict__ w, uint16_t* __restrict__ wb) {
  int i = blockIdx.x*256 + threadIdx.x;   // 1024 blocks
  float4 v = *(const float4*)&w[i*4];
  uint16_t o[4] = {f2bf(v.x), f2bf(v.y), f2bf(v.z), f2bf(v.w)};
  *(uint64_t*)&wb[i*4] = *(const uint64_t*)o;
}

// ---------- pass A: argmax_n (x . g_n), fp32, + counts ----------
// Latency-bound fix (R3): c-loop unrolled x16 with an explicit two-phase register
// double-buffer -- 8 x-loads in flight while the other 8 feed 128 FMAs. FMA order
// over c is unchanged (ascending), so results are bitwise identical to the
// previous version. VGPR ~40, occupancy still grid-limited at 8 waves/CU.
__launch_bounds__(256)
__global__ void pass_assign(const float* __restrict__ x, const float* __restrict__ gT,
                            int* __restrict__ idx, int* __restrict__ count) {
  int bb = blockIdx.x >> 6;      // grid 512 = 8 b * 64 ptiles
  int pt = blockIdx.x & 63;
  int t = threadIdx.x;
  int lane = t & 63;
  int ng = __builtin_amdgcn_readfirstlane(t >> 6);  // wave id = n-group (uniform -> s_loads of g)
  const float* xp = x + (size_t)bb*C_*HW_ + pt*64 + lane;
  const float* gp = gT + ng*16;
  float acc[16];
  #pragma unroll
  for (int n = 0; n < 16; n++) acc[n] = 0.f;

  float xa[8], xb2[8];
  #pragma unroll
  for (int u = 0; u < 8; u++) xa[u] = xp[(size_t)u*HW_];
  for (int cb = 0; cb < C_; cb += 16) {
    // prefetch second half of this 16-chunk while first half computes
    #pragma unroll
    for (int u = 0; u < 8; u++) xb2[u] = xp[(size_t)(cb + 8 + u)*HW_];
    #pragma unroll
    for (int u = 0; u < 8; u++) {
      const float* gr = gp + (cb + u)*K_;      // wave-uniform -> s_load
      #pragma unroll
      for (int n = 0; n < 16; n++) acc[n] = fmaf(xa[u], gr[n], acc[n]);
    }
    // prefetch first half of next 16-chunk while second half computes
    if (cb + 16 < C_) {
      #pragma unroll
      for (int u = 0; u < 8; u++) xa[u] = xp[(size_t)(cb + 16 + u)*HW_];
    }
    #pragma unroll
    for (int u = 0; u < 8; u++) {
      const float* gr = gp + (cb + 8 + u)*K_;
      #pragma unroll
      for (int n = 0; n < 16; n++) acc[n] = fmaf(xb2[u], gr[n], acc[n]);
    }
  }

  float best = acc[0]; int bi = 0;
  #pragma unroll
  for (int n = 1; n < 16; n++) { if (acc[n] > best) { best = acc[n]; bi = n; } }
  __shared__ float bv[4][64];
  __shared__ int   bn[4][64];
  __shared__ int   hist[64];
  if (t < 64) hist[t] = 0;
  bv[ng][lane] = best; bn[ng][lane] = ng*16 + bi;
  __syncthreads();
  if (t < 64) {
    float mv = bv[0][t]; int mn = bn[0][t];
    #pragma unroll
    for (int wv2 = 1; wv2 < 4; wv2++) { if (bv[wv2][t] > mv) { mv = bv[wv2][t]; mn = bn[wv2][t]; } }
    idx[bb*HW_ + pt*64 + t] = mn;
    atomicAdd(&hist[mn], 1);
  }
  __syncthreads();
  if (t < 64 && hist[t] > 0) atomicAdd(&count[bb*K_ + t], hist[t]);
}

// ---------- pass B: sum_x[b,n,c] partials as a one-hot bf16 MFMA GEMM ----------
// D[c][n] = sum_p X[c][p] * onehot[p][n]. A-frags come straight from x's [c][p]
// layout (8 consecutive pixels per lane, same fragment convention as gemm_out);
// B one-hot frags are generated IN REGISTERS from idx (2 VALU/elem). No LDS, no
// atomics -- this removes the serialized LDS-atomic RMW chain that capped the
// scatter version at ~184us regardless of occupancy.
// grid 1024 = 8 b * 16 ctiles(64 rows) * 8 psegs(512 pixels).
__launch_bounds__(256)
__global__ void pass_bins(const float* __restrict__ x, const int* __restrict__ idx,
                          float* __restrict__ sumxp) {
  int bid = blockIdx.x;
  int ps = bid & 7;              // pixel segment (512 pixels)
  int ct = (bid >> 3) & 15;      // c tile (64 rows)
  int bb = bid >> 7;             // batch
  int t = threadIdx.x;
  int lane = t & 63;
  int w = t >> 6;                // wave -> 16 c-rows
  int col = lane & 15;
  int kg  = lane >> 4;           // k-group: 8 consecutive pixels per lane
  int crow = ct*64 + w*16 + col;
  const float* xp = x + (size_t)bb*C_*HW_ + (size_t)crow*HW_ + ps*512 + kg*8;
  const int*   ip = idx + bb*HW_ + ps*512 + kg*8;

  const f32x4 fzero = {0.f, 0.f, 0.f, 0.f};
  f32x4 acc[4];
  #pragma unroll
  for (int f = 0; f < 4; f++) acc[f] = fzero;

  for (int ks = 0; ks < 16; ks++) {
    // A: 8 consecutive pixels of this c-row, fp32 -> bf16
    float a0[8];
    *(float4*)&a0[0] = *(const float4*)&xp[ks*32];
    *(float4*)&a0[4] = *(const float4*)&xp[ks*32 + 4];
    short8 af;
    #pragma unroll
    for (int j = 0; j < 8; j++) af[j] = (short)f2bf(a0[j]);
    // cluster ids of those 8 pixels (same 32B broadcast across a 16-lane group)
    int iv8[8];
    *(int4*)&iv8[0] = *(const int4*)&ip[ks*32];
    *(int4*)&iv8[4] = *(const int4*)&ip[ks*32 + 4];
    // 4 one-hot B frags cover n = 0..63 (bf16 1.0 = 0x3F80, exact)
    #pragma unroll
    for (int f = 0; f < 4; f++) {
      int n = f*16 + col;
      short8 bfrag;
      #pragma unroll
      for (int j = 0; j < 8; j++) bfrag[j] = (short)((iv8[j] == n) ? 0x3F80 : 0);
      acc[f] = __builtin_amdgcn_mfma_f32_16x16x32_bf16(af, bfrag, acc[f], 0, 0, 0);
    }
  }
  // C/D layout: col = lane&15 (-> n within frag), row = (lane>>4)*4 + reg (-> c-row)
  #pragma unroll
  for (int f = 0; f < 4; f++) {
    int n = f*16 + col;
    size_t base = (size_t)ps*SLAB + ((size_t)bb*K_ + n)*C_ + ct*64 + w*16 + kg*4;
    *(f32x4*)&sumxp[base] = acc[f];   // 16B aligned; lanes of one n fill a 64B line
  }
}

// ---------- pass B2: c_local, c_localT, ||c||^2 (sums the 8 pixel-segment slabs) ----------
__launch_bounds__(256)
__global__ void pass_cfinal(const float* __restrict__ sumxp, const int* __restrict__ count,
                            float* __restrict__ cl, float* __restrict__ clT,
                            float* __restrict__ cn2) {
  int bb = blockIdx.x >> 6, n = blockIdx.x & 63, t = threadIdx.x;  // grid 512
  float inv = 1.f / fmaxf((float)count[bb*K_ + n], 1.f);
  float ss = 0.f;
  #pragma unroll
  for (int i = 0; i < 4; i++) {
    int c = t + i*256;
    size_t o = ((size_t)bb*K_ + n)*C_ + c;
    float v = 0.f;
    #pragma unroll
    for (int s = 0; s < NSEG; s++) v += sumxp[o + (size_t)s*SLAB];
    v *= inv;
    cl [((size_t)bb*K_ + n)*C_ + c] = v;
    clT[((size_t)bb*C_ + c)*K_ + n] = v;
    ss += v*v;
  }
  __shared__ float red[256];
  red[t] = ss; __syncthreads();
  for (int s = 128; s > 0; s >>= 1) { if (t < s) red[t] += red[t+s]; __syncthreads(); }
  if (t == 0) cn2[bb*K_ + n] = red[0];
}

// ---------- pass C0: w[p] then x_cal bf16, transposed [pixel][c] ----------
__launch_bounds__(256)
__global__ void pass_xcal(const float* __restrict__ x, const int* __restrict__ idx,
                          const float* __restrict__ cl, const float* __restrict__ clT,
                          const float* __restrict__ cn2, uint16_t* __restrict__ xcal) {
  int bb = blockIdx.x >> 6, pt = blockIdx.x & 63, t = threadIdx.x;  // grid 512: 64-pixel tiles
  int lane = t & 63, cs = t >> 6;
  __shared__ float xT[64][129];
  __shared__ int   widx[64];
  __shared__ float pdot[4][64], pxsq[4][64], wv[64];
  if (t < 64) widx[t] = idx[bb*HW_ + pt*64 + t];
  __syncthreads();
  const float* xb = x + (size_t)bb*C_*HW_ + pt*64;
  // phase 1: direct per-pixel dot; lane = pixel, wave = c-strip. Coalesced x, 256B clT gather rows.
  int myi = widx[lane];
  const float* clb = clT + (size_t)bb*C_*K_ + myi;
  float dp = 0.f, xq = 0.f;
  #pragma unroll 4
  for (int ci = 0; ci < 256; ci++) {
    int c = cs*256 + ci;
    float xv = xb[(size_t)c*HW_ + lane];
    dp = fmaf(xv, clb[(size_t)c*K_], dp);
    xq = fmaf(xv, xv, xq);
  }
  pdot[cs][lane] = dp; pxsq[cs][lane] = xq;
  __syncthreads();
  if (t < 64) {
    float d = pdot[0][t]+pdot[1][t]+pdot[2][t]+pdot[3][t];
    float q = pxsq[0][t]+pxsq[1][t]+pxsq[2][t]+pxsq[3][t];
    float msd = (q - 2.f*d + cn2[bb*K_ + widx[t]]) * (1.f/1024.f);
    wv[t] = expf(-msd);
  }
  __syncthreads();
  // phase 2: transpose-write bf16 [pixel][c] (x tiles re-read; L2-hot from phase 1)
  for (int cc = 0; cc < 8; cc++) {
    #pragma unroll
    for (int i = 0; i < 32; i++) {
      int co = cs*32 + i;
      xT[lane][co] = xb[(size_t)(cc*128 + co)*HW_ + lane];
    }
    __syncthreads();
    #pragma unroll 2
    for (int pp = 0; pp < 16; pp++) {
      int p = pp*4 + cs;
      float wval = wv[p]; int iv = widx[p];
      const float* clr = cl + ((size_t)bb*K_ + iv)*C_ + cc*128;
      size_t obase = ((size_t)(bb*HW_ + pt*64 + p))*C_ + cc*128;
      #pragma unroll
      for (int ci = 0; ci < 2; ci++) {
        int co = ci*64 + lane;
        float xvv = xT[p][co];
        float v = fmaf(wval, clr[co] - xvv, xvv);   // x + w*(c-x)
        xcal[obase + co] = f2bf(v);
      }
    }
    __syncthreads();
  }
}

// ---------- pass C: out = relu(W @ x_cal + bias), bf16 MFMA, one 128x128 tile/block ----------
#define BK 64
__launch_bounds__(256)
__global__ void gemm_out(const uint16_t* __restrict__ wb, const uint16_t* __restrict__ xcal,
                         const float* __restrict__ bias, float* __restrict__ out) {
  // 32 KB total: lw|lx during K-loop, aliased by the 32 KB epilogue transpose buffer after.
  __shared__ alignas(16) uint16_t smem[2*128*BK];
  uint16_t* lw = smem;
  uint16_t* lx = smem + 128*BK;
  float*    ep = (float*)smem;
  int t = threadIdx.x;
  int lane = t & 63;
  int w = t >> 6, wm = w & 1, wn = w >> 1;
  // XCD swizzle: xcd = bid&7; within an XCD, ot fastest -> 8 blocks sharing an xcal
  // tile run consecutively on the SAME XCD (xcal tile + all 8 W tiles stay L2-hot).
  int g  = blockIdx.x & 7;
  int li = blockIdx.x >> 3;
  int ot = li & 7;
  int qt = g*32 + (li >> 3);

  const uint16_t* wsrc = wb   + (size_t)ot*128*C_;
  const uint16_t* xsrc = xcal + (size_t)qt*128*C_;

  const f32x4 fzero = {0.f, 0.f, 0.f, 0.f};
  f32x4 acc[4][4];
  #pragma unroll
  for (int i = 0; i < 4; i++)
    #pragma unroll
    for (int j = 0; j < 4; j++) acc[i][j] = fzero;

  for (int kb = 0; kb < C_/BK; kb++) {
    #pragma unroll
    for (int it = 0; it < 4; it++) {
      int s = t + it*256;              // 1024 slots of 16B per tile
      int r = s >> 3, q = s & 7;
      int qm = q ^ (r & 7);            // inverse swizzle on the global side
      uint16_t* ldw = lw + (size_t)(it*256 + w*64)*8;   // wave-uniform base
      uint16_t* ldx = lx + (size_t)(it*256 + w*64)*8;
      gl2lds16(wsrc + (size_t)r*C_ + kb*BK + qm*8, ldw);
      gl2lds16(xsrc + (size_t)r*C_ + kb*BK + qm*8, ldx);
    }
    __syncthreads();                   // drains vmcnt -> LDS tiles ready
    #pragma unroll
    for (int kk = 0; kk < 2; kk++) {
      short8 af[4], bf[4];
      #pragma unroll
      for (int i = 0; i < 4; i++) {
        int row = wm*64 + i*16 + (lane & 15);
        int q = kk*4 + (lane >> 4);
        af[i] = *(const short8*)&lw[row*BK + (q ^ (row & 7))*8];
      }
      #pragma unroll
      for (int j = 0; j < 4; j++) {
        int row = wn*64 + j*16 + (lane & 15);
        int q = kk*4 + (lane >> 4);
        bf[j] = *(const short8*)&lx[row*BK + (q ^ (row & 7))*8];
      }
      #pragma unroll
      for (int i = 0; i < 4; i++)
        #pragma unroll
        for (int j = 0; j < 4; j++)
          acc[i][j] = __builtin_amdgcn_mfma_f32_16x16x32_bf16(af[i], bf[j], acc[i][j], 0, 0, 0);
    }
    __syncthreads();                   // all reads done before next kb's DMA lands
  }
  // epilogue: LDS transpose (aliases lw/lx -- safe after final barrier) -> float4 row stores
  int col = lane & 15, quad = lane >> 4;
  int bq = (qt*128) >> 12;
  int p0 = (qt*128) & 4095;
  #pragma unroll
  for (int ph = 0; ph < 2; ph++) {
    if (wm == ph) {
      #pragma unroll
      for (int i = 0; i < 4; i++)
        #pragma unroll
        for (int j = 0; j < 4; j++) {
          int p = wn*64 + j*16 + col;
          #pragma unroll
          for (int r = 0; r < 4; r++) {
            int o2 = i*16 + quad*4 + r;   // local o within 64
            ep[o2*128 + (((p >> 2) ^ (o2 & 7)) << 2) + (p & 3)] = acc[i][j][r];
          }
        }
    }
    __syncthreads();
    #pragma unroll
    for (int i2 = 0; i2 < 8; i2++) {
      int s = t + i2*256;
      int ol = s >> 5, pf = s & 31;
      float4 v = *(const float4*)&ep[ol*128 + ((pf ^ (ol & 7)) << 2)];
      int o = ot*128 + ph*64 + ol;
      float bi = bias[o];
      v.x = fmaxf(v.x + bi, 0.f); v.y = fmaxf(v.y + bi, 0.f);
      v.z = fmaxf(v.z + bi, 0.f); v.w = fmaxf(v.w + bi, 0.f);
      *(float4*)&out[(size_t)bq*C_*HW_ + (size_t)o*HW_ + p0 + pf*4] = v;
    }
    __syncthreads();
  }
}

extern "C" void kernel_launch(void* const* d_in, const int* in_sizes, int n_in,
                              void* d_out, int out_size, void* d_ws, size_t ws_size,
                              hipStream_t stream) {
  (void)in_sizes; (void)n_in; (void)out_size; (void)ws_size;
  const float* x    = (const float*)d_in[0];
  const float* cent = (const float*)d_in[1];
  const float* fw   = (const float*)d_in[2];
  const float* fb   = (const float*)d_in[3];
  float* out = (float*)d_out;
  char* ws = (char*)d_ws;
  size_t off = 0;
  float*    gT    = (float*)(ws + off);    off += (size_t)C_*K_*4;        // 256 KB
  int*      idx   = (int*)(ws + off);      off += (size_t)NPIX*4;         // 128 KB
  int*      count = (int*)(ws + off);      off += (size_t)B_*K_*4;        // 2 KB
  float*    sumx  = (float*)(ws + off);    off += (size_t)B_*K_*C_*4;     // 2 MB (unused; keeps offsets identical)
  float*    cl    = (float*)(ws + off);    off += (size_t)B_*K_*C_*4;     // 2 MB
  float*    clT   = (float*)(ws + off);    off += (size_t)B_*C_*K_*4;     // 2 MB
  float*    cn2   = (float*)(ws + off);    off += (size_t)B_*K_*4 + 8;    // 2 KB (+pad->16B)
  uint16_t* wb    = (uint16_t*)(ws + off); off += (size_t)C_*C_*2;        // 2 MB
  uint16_t* xcal  = (uint16_t*)(ws + off); off += (size_t)NPIX*C_*2;      // 64 MB
  (void)sumx;
  // partial-sum slabs (8 x 2 MB) alias the xcal region: dead once pass_cfinal reads them,
  // and pass_xcal only writes xcal afterwards.
  float* sumxp = (float*)xcal;

  hipMemsetAsync(count, 0, (size_t)B_*K_*4, stream);
  prep_gT   <<<64,   256, 0, stream>>>(cent, gT);
  prep_wb   <<<1024, 256, 0, stream>>>(fw, wb);
  pass_assign<<<512, 256, 0, stream>>>(x, gT, idx, count);
  pass_bins <<<1024, 256, 0, stream>>>(x, idx, sumxp);
  pass_cfinal<<<512, 256, 0, stream>>>(sumxp, count, cl, clT, cn2);
  pass_xcal <<<512,  256, 0, stream>>>(x, idx, cl, clT, cn2, xcal);
  gemm_out  <<<2048, 256, 0, stream>>>(wb, xcal, fb, out);
}

// Round 4
// 534.203 us; speedup vs baseline: 1.4143x; 1.0297x over previous
//
#include <hip/hip_runtime.h>
#include <stdint.h>

#define B_   8
#define C_   1024
#define HW_  4096
#define K_   64
#define NPIX (B_*HW_)
#define SLAB ((size_t)B_*K_*C_)
#define NSEG 8

typedef __attribute__((ext_vector_type(8))) short short8;
typedef __attribute__((ext_vector_type(4))) float f32x4;

__device__ __forceinline__ uint16_t f2bf(float f) {
  uint32_t u = __float_as_uint(f);
  u += 0x7fffu + ((u >> 16) & 1u);   // round-to-nearest-even
  return (uint16_t)(u >> 16);
}

// async global -> LDS, 16B per lane. LDS dest must be wave-uniform base; lane deposits at base+lane*16.
__device__ __forceinline__ void gl2lds16(const uint16_t* g, uint16_t* l) {
  __builtin_amdgcn_global_load_lds(
      (const __attribute__((address_space(1))) unsigned int*)(g),
      (__attribute__((address_space(3))) unsigned int*)(l), 16, 0, 0);
}

// ---------- prep: normalized centroids, transposed gT[c][n] ----------
__global__ void prep_gT(const float* __restrict__ g, float* __restrict__ gT) {
  int n = blockIdx.x;            // 64 blocks
  int t = threadIdx.x;           // 256 threads
  float vals[4]; float ss = 0.f;
  #pragma unroll
  for (int i = 0; i < 4; i++) { float v = g[n*C_ + t + i*256]; vals[i] = v; ss += v*v; }
  __shared__ float red[256];
  red[t] = ss; __syncthreads();
  for (int s = 128; s > 0; s >>= 1) { if (t < s) red[t] += red[t+s]; __syncthreads(); }
  float scale = 1.f / fmaxf(sqrtf(red[0]), 1e-12f);
  #pragma unroll
  for (int i = 0; i < 4; i++) gT[(t + i*256)*K_ + n] = vals[i]*scale;
}

// ---------- prep: fc_weight fp32 -> bf16 row-major [o][c], 4 elems/thread ----------
__global__ void prep_wb(const float* __restrict__ w, uint16_t* __restrict__ wb) {
  int i = blockIdx.x*256 + threadIdx.x;   // 1024 blocks
  float4 v = *(const float4*)&w[i*4];
  uint16_t o[4] = {f2bf(v.x), f2bf(v.y), f2bf(v.z), f2bf(v.w)};
  *(uint64_t*)&wb[i*4] = *(const uint64_t*)o;
}

// ---------- pass A: argmax_n (x . g_n), fp32, + counts ----------
// c-loop unrolled x16 with a two-phase register double-buffer: 8 x-loads in
// flight while the other 8 feed 128 FMAs. FMA order over c unchanged.
__launch_bounds__(256)
__global__ void pass_assign(const float* __restrict__ x, const float* __restrict__ gT,
                            int* __restrict__ idx, int* __restrict__ count) {
  int bb = blockIdx.x >> 6;      // grid 512 = 8 b * 64 ptiles
  int pt = blockIdx.x & 63;
  int t = threadIdx.x;
  int lane = t & 63;
  int ng = __builtin_amdgcn_readfirstlane(t >> 6);  // wave id = n-group (uniform -> s_loads of g)
  const float* xp = x + (size_t)bb*C_*HW_ + pt*64 + lane;
  const float* gp = gT + ng*16;
  float acc[16];
  #pragma unroll
  for (int n = 0; n < 16; n++) acc[n] = 0.f;

  float xa[8], xb2[8];
  #pragma unroll
  for (int u = 0; u < 8; u++) xa[u] = xp[(size_t)u*HW_];
  for (int cb = 0; cb < C_; cb += 16) {
    // prefetch second half of this 16-chunk while first half computes
    #pragma unroll
    for (int u = 0; u < 8; u++) xb2[u] = xp[(size_t)(cb + 8 + u)*HW_];
    #pragma unroll
    for (int u = 0; u < 8; u++) {
      const float* gr = gp + (cb + u)*K_;      // wave-uniform -> s_load
      #pragma unroll
      for (int n = 0; n < 16; n++) acc[n] = fmaf(xa[u], gr[n], acc[n]);
    }
    // prefetch first half of next 16-chunk while second half computes
    if (cb + 16 < C_) {
      #pragma unroll
      for (int u = 0; u < 8; u++) xa[u] = xp[(size_t)(cb + 16 + u)*HW_];
    }
    #pragma unroll
    for (int u = 0; u < 8; u++) {
      const float* gr = gp + (cb + 8 + u)*K_;
      #pragma unroll
      for (int n = 0; n < 16; n++) acc[n] = fmaf(xb2[u], gr[n], acc[n]);
    }
  }

  float best = acc[0]; int bi = 0;
  #pragma unroll
  for (int n = 1; n < 16; n++) { if (acc[n] > best) { best = acc[n]; bi = n; } }
  __shared__ float bv[4][64];
  __shared__ int   bn[4][64];
  __shared__ int   hist[64];
  if (t < 64) hist[t] = 0;
  bv[ng][lane] = best; bn[ng][lane] = ng*16 + bi;
  __syncthreads();
  if (t < 64) {
    float mv = bv[0][t]; int mn = bn[0][t];
    #pragma unroll
    for (int wv2 = 1; wv2 < 4; wv2++) { if (bv[wv2][t] > mv) { mv = bv[wv2][t]; mn = bn[wv2][t]; } }
    idx[bb*HW_ + pt*64 + t] = mn;
    atomicAdd(&hist[mn], 1);
  }
  __syncthreads();
  if (t < 64 && hist[t] > 0) atomicAdd(&count[bb*K_ + t], hist[t]);
}

// ---------- pass B: sum_x[b,n,c] partials as a one-hot bf16 MFMA GEMM ----------
// D[c][n] = sum_p X[c][p] * onehot[p][n]. No LDS, no atomics.
// grid 1024 = 8 b * 16 ctiles(64 rows) * 8 psegs(512 pixels).
__launch_bounds__(256)
__global__ void pass_bins(const float* __restrict__ x, const int* __restrict__ idx,
                          float* __restrict__ sumxp) {
  int bid = blockIdx.x;
  int ps = bid & 7;              // pixel segment (512 pixels)
  int ct = (bid >> 3) & 15;      // c tile (64 rows)
  int bb = bid >> 7;             // batch
  int t = threadIdx.x;
  int lane = t & 63;
  int w = t >> 6;                // wave -> 16 c-rows
  int col = lane & 15;
  int kg  = lane >> 4;           // k-group: 8 consecutive pixels per lane
  int crow = ct*64 + w*16 + col;
  const float* xp = x + (size_t)bb*C_*HW_ + (size_t)crow*HW_ + ps*512 + kg*8;
  const int*   ip = idx + bb*HW_ + ps*512 + kg*8;

  const f32x4 fzero = {0.f, 0.f, 0.f, 0.f};
  f32x4 acc[4];
  #pragma unroll
  for (int f = 0; f < 4; f++) acc[f] = fzero;

  for (int ks = 0; ks < 16; ks++) {
    // A: 8 consecutive pixels of this c-row, fp32 -> bf16
    float a0[8];
    *(float4*)&a0[0] = *(const float4*)&xp[ks*32];
    *(float4*)&a0[4] = *(const float4*)&xp[ks*32 + 4];
    short8 af;
    #pragma unroll
    for (int j = 0; j < 8; j++) af[j] = (short)f2bf(a0[j]);
    // cluster ids of those 8 pixels (same 32B broadcast across a 16-lane group)
    int iv8[8];
    *(int4*)&iv8[0] = *(const int4*)&ip[ks*32];
    *(int4*)&iv8[4] = *(const int4*)&ip[ks*32 + 4];
    // 4 one-hot B frags cover n = 0..63 (bf16 1.0 = 0x3F80, exact)
    #pragma unroll
    for (int f = 0; f < 4; f++) {
      int n = f*16 + col;
      short8 bfrag;
      #pragma unroll
      for (int j = 0; j < 8; j++) bfrag[j] = (short)((iv8[j] == n) ? 0x3F80 : 0);
      acc[f] = __builtin_amdgcn_mfma_f32_16x16x32_bf16(af, bfrag, acc[f], 0, 0, 0);
    }
  }
  // C/D layout: col = lane&15 (-> n within frag), row = (lane>>4)*4 + reg (-> c-row)
  #pragma unroll
  for (int f = 0; f < 4; f++) {
    int n = f*16 + col;
    size_t base = (size_t)ps*SLAB + ((size_t)bb*K_ + n)*C_ + ct*64 + w*16 + kg*4;
    *(f32x4*)&sumxp[base] = acc[f];   // 16B aligned; lanes of one n fill a 64B line
  }
}

// ---------- pass B2: c_local, c_localT, ||c||^2 (sums the 8 pixel-segment slabs) ----------
__launch_bounds__(256)
__global__ void pass_cfinal(const float* __restrict__ sumxp, const int* __restrict__ count,
                            float* __restrict__ cl, float* __restrict__ clT,
                            float* __restrict__ cn2) {
  int bb = blockIdx.x >> 6, n = blockIdx.x & 63, t = threadIdx.x;  // grid 512
  float inv = 1.f / fmaxf((float)count[bb*K_ + n], 1.f);
  float ss = 0.f;
  #pragma unroll
  for (int i = 0; i < 4; i++) {
    int c = t + i*256;
    size_t o = ((size_t)bb*K_ + n)*C_ + c;
    float v = 0.f;
    #pragma unroll
    for (int s = 0; s < NSEG; s++) v += sumxp[o + (size_t)s*SLAB];
    v *= inv;
    cl [((size_t)bb*K_ + n)*C_ + c] = v;
    clT[((size_t)bb*C_ + c)*K_ + n] = v;
    ss += v*v;
  }
  __shared__ float red[256];
  red[t] = ss; __syncthreads();
  for (int s = 128; s > 0; s >>= 1) { if (t < s) red[t] += red[t+s]; __syncthreads(); }
  if (t == 0) cn2[bb*K_ + n] = red[0];
}

// ---------- pass C0: w[p] then x_cal bf16, transposed [pixel][c] ----------
__launch_bounds__(256)
__global__ void pass_xcal(const float* __restrict__ x, const int* __restrict__ idx,
                          const float* __restrict__ cl, const float* __restrict__ clT,
                          const float* __restrict__ cn2, uint16_t* __restrict__ xcal) {
  int bb = blockIdx.x >> 6, pt = blockIdx.x & 63, t = threadIdx.x;  // grid 512: 64-pixel tiles
  int lane = t & 63, cs = t >> 6;
  __shared__ float xT[64][129];
  __shared__ int   widx[64];
  __shared__ float pdot[4][64], pxsq[4][64], wv[64];
  if (t < 64) widx[t] = idx[bb*HW_ + pt*64 + t];
  __syncthreads();
  const float* xb = x + (size_t)bb*C_*HW_ + pt*64;
  // phase 1: direct per-pixel dot; lane = pixel, wave = c-strip. Coalesced x, 256B clT gather rows.
  int myi = widx[lane];
  const float* clb = clT + (size_t)bb*C_*K_ + myi;
  float dp = 0.f, xq = 0.f;
  #pragma unroll 4
  for (int ci = 0; ci < 256; ci++) {
    int c = cs*256 + ci;
    float xv = xb[(size_t)c*HW_ + lane];
    dp = fmaf(xv, clb[(size_t)c*K_], dp);
    xq = fmaf(xv, xv, xq);
  }
  pdot[cs][lane] = dp; pxsq[cs][lane] = xq;
  __syncthreads();
  if (t < 64) {
    float d = pdot[0][t]+pdot[1][t]+pdot[2][t]+pdot[3][t];
    float q = pxsq[0][t]+pxsq[1][t]+pxsq[2][t]+pxsq[3][t];
    float msd = (q - 2.f*d + cn2[bb*K_ + widx[t]]) * (1.f/1024.f);
    wv[t] = expf(-msd);
  }
  __syncthreads();
  // phase 2: transpose-write bf16 [pixel][c] (x tiles re-read; L2-hot from phase 1)
  for (int cc = 0; cc < 8; cc++) {
    #pragma unroll
    for (int i = 0; i < 32; i++) {
      int co = cs*32 + i;
      xT[lane][co] = xb[(size_t)(cc*128 + co)*HW_ + lane];
    }
    __syncthreads();
    #pragma unroll 2
    for (int pp = 0; pp < 16; pp++) {
      int p = pp*4 + cs;
      float wval = wv[p]; int iv = widx[p];
      const float* clr = cl + ((size_t)bb*K_ + iv)*C_ + cc*128;
      size_t obase = ((size_t)(bb*HW_ + pt*64 + p))*C_ + cc*128;
      #pragma unroll
      for (int ci = 0; ci < 2; ci++) {
        int co = ci*64 + lane;
        float xvv = xT[p][co];
        float v = fmaf(wval, clr[co] - xvv, xvv);   // x + w*(c-x)
        xcal[obase + co] = f2bf(v);
      }
    }
    __syncthreads();
  }
}

// ---------- pass C: out = relu(W @ x_cal + bias), bf16 MFMA, one 128x128 tile/block ----------
// R4: explicit LDS double-buffer (T3 minimum 2-phase). STAGE(kb+1) is issued
// BEFORE the ds_read+MFMA of kb, and there is ONE __syncthreads() per K-step:
// its vmcnt(0) drain lands after 32 MFMAs, hiding the stage latency. The
// barrier also guarantees all waves' ds_reads of the buffer we stage into
// next completed (lgkmcnt drained per-wave before barrier). MFMA order is
// unchanged -> bitwise-identical results.
#define BK 64
__launch_bounds__(256)
__global__ void gemm_out(const uint16_t* __restrict__ wb, const uint16_t* __restrict__ xcal,
                         const float* __restrict__ bias, float* __restrict__ out) {
  // 64 KB: 2 buffers x (lw 16KB + lx 16KB). Epilogue ep (32 KB) aliases buf0.
  __shared__ alignas(16) uint16_t smem[2*2*128*BK];
  float* ep = (float*)smem;
  int t = threadIdx.x;
  int lane = t & 63;
  int w = t >> 6, wm = w & 1, wn = w >> 1;
  // XCD swizzle: xcd = bid&7; within an XCD, ot fastest -> 8 blocks sharing an xcal
  // tile run consecutively on the SAME XCD (xcal tile + all 8 W tiles stay L2-hot).
  int g  = blockIdx.x & 7;
  int li = blockIdx.x >> 3;
  int ot = li & 7;
  int qt = g*32 + (li >> 3);

  const uint16_t* wsrc = wb   + (size_t)ot*128*C_;
  const uint16_t* xsrc = xcal + (size_t)qt*128*C_;

  const f32x4 fzero = {0.f, 0.f, 0.f, 0.f};
  f32x4 acc[4][4];
  #pragma unroll
  for (int i = 0; i < 4; i++)
    #pragma unroll
    for (int j = 0; j < 4; j++) acc[i][j] = fzero;

  // stage one 128x64 W-tile + 128x64 X-tile into buffer `buf`
  auto STAGE = [&](int buf, int kb) {
    uint16_t* lw = smem + (size_t)buf*2*128*BK;
    uint16_t* lx = lw + 128*BK;
    #pragma unroll
    for (int it = 0; it < 4; it++) {
      int s = t + it*256;              // 1024 slots of 16B per tile
      int r = s >> 3, q = s & 7;
      int qm = q ^ (r & 7);            // inverse swizzle on the global side
      uint16_t* ldw = lw + (size_t)(it*256 + w*64)*8;   // wave-uniform base
      uint16_t* ldx = lx + (size_t)(it*256 + w*64)*8;
      gl2lds16(wsrc + (size_t)r*C_ + kb*BK + qm*8, ldw);
      gl2lds16(xsrc + (size_t)r*C_ + kb*BK + qm*8, ldx);
    }
  };

  STAGE(0, 0);
  __syncthreads();                     // vmcnt(0) drain: buf0 ready
  for (int kb = 0; kb < C_/BK; kb++) {
    int cur = kb & 1;
    if (kb + 1 < C_/BK) STAGE(cur ^ 1, kb + 1);   // loads fly during compute below
    const uint16_t* lw = smem + (size_t)cur*2*128*BK;
    const uint16_t* lx = lw + 128*BK;
    #pragma unroll
    for (int kk = 0; kk < 2; kk++) {
      short8 af[4], bf[4];
      #pragma unroll
      for (int i = 0; i < 4; i++) {
        int row = wm*64 + i*16 + (lane & 15);
        int q = kk*4 + (lane >> 4);
        af[i] = *(const short8*)&lw[row*BK + (q ^ (row & 7))*8];
      }
      #pragma unroll
      for (int j = 0; j < 4; j++) {
        int row = wn*64 + j*16 + (lane & 15);
        int q = kk*4 + (lane >> 4);
        bf[j] = *(const short8*)&lx[row*BK + (q ^ (row & 7))*8];
      }
      #pragma unroll
      for (int i = 0; i < 4; i++)
        #pragma unroll
        for (int j = 0; j < 4; j++)
          acc[i][j] = __builtin_amdgcn_mfma_f32_16x16x32_bf16(af[i], bf[j], acc[i][j], 0, 0, 0);
    }
    __syncthreads();   // drains vmcnt (next buf landed) + all waves done reading cur
  }
  // epilogue: LDS transpose (aliases buf0 -- safe after final barrier) -> float4 row stores
  int col = lane & 15, quad = lane >> 4;
  int bq = (qt*128) >> 12;
  int p0 = (qt*128) & 4095;
  #pragma unroll
  for (int ph = 0; ph < 2; ph++) {
    if (wm == ph) {
      #pragma unroll
      for (int i = 0; i < 4; i++)
        #pragma unroll
        for (int j = 0; j < 4; j++) {
          int p = wn*64 + j*16 + col;
          #pragma unroll
          for (int r = 0; r < 4; r++) {
            int o2 = i*16 + quad*4 + r;   // local o within 64
            ep[o2*128 + (((p >> 2) ^ (o2 & 7)) << 2) + (p & 3)] = acc[i][j][r];
          }
        }
    }
    __syncthreads();
    #pragma unroll
    for (int i2 = 0; i2 < 8; i2++) {
      int s = t + i2*256;
      int ol = s >> 5, pf = s & 31;
      float4 v = *(const float4*)&ep[ol*128 + ((pf ^ (ol & 7)) << 2)];
      int o = ot*128 + ph*64 + ol;
      float bi = bias[o];
      v.x = fmaxf(v.x + bi, 0.f); v.y = fmaxf(v.y + bi, 0.f);
      v.z = fmaxf(v.z + bi, 0.f); v.w = fmaxf(v.w + bi, 0.f);
      *(float4*)&out[(size_t)bq*C_*HW_ + (size_t)o*HW_ + p0 + pf*4] = v;
    }
    __syncthreads();
  }
}

extern "C" void kernel_launch(void* const* d_in, const int* in_sizes, int n_in,
                              void* d_out, int out_size, void* d_ws, size_t ws_size,
                              hipStream_t stream) {
  (void)in_sizes; (void)n_in; (void)out_size; (void)ws_size;
  const float* x    = (const float*)d_in[0];
  const float* cent = (const float*)d_in[1];
  const float* fw   = (const float*)d_in[2];
  const float* fb   = (const float*)d_in[3];
  float* out = (float*)d_out;
  char* ws = (char*)d_ws;
  size_t off = 0;
  float*    gT    = (float*)(ws + off);    off += (size_t)C_*K_*4;        // 256 KB
  int*      idx   = (int*)(ws + off);      off += (size_t)NPIX*4;         // 128 KB
  int*      count = (int*)(ws + off);      off += (size_t)B_*K_*4;        // 2 KB
  float*    sumx  = (float*)(ws + off);    off += (size_t)B_*K_*C_*4;     // 2 MB (unused; keeps offsets identical)
  float*    cl    = (float*)(ws + off);    off += (size_t)B_*K_*C_*4;     // 2 MB
  float*    clT   = (float*)(ws + off);    off += (size_t)B_*C_*K_*4;     // 2 MB
  float*    cn2   = (float*)(ws + off);    off += (size_t)B_*K_*4 + 8;    // 2 KB (+pad->16B)
  uint16_t* wb    = (uint16_t*)(ws + off); off += (size_t)C_*C_*2;        // 2 MB
  uint16_t* xcal  = (uint16_t*)(ws + off); off += (size_t)NPIX*C_*2;     // 64 MB
  (void)sumx;
  // partial-sum slabs (8 x 2 MB) alias the xcal region: dead once pass_cfinal reads them,
  // and pass_xcal only writes xcal afterwards.
  float* sumxp = (float*)xcal;

  hipMemsetAsync(count, 0, (size_t)B_*K_*4, stream);
  prep_gT   <<<64,   256, 0, stream>>>(cent, gT);
  prep_wb   <<<1024, 256, 0, stream>>>(fw, wb);
  pass_assign<<<512, 256, 0, stream>>>(x, gT, idx, count);
  pass_bins <<<1024, 256, 0, stream>>>(x, idx, sumxp);
  pass_cfinal<<<512, 256, 0, stream>>>(sumxp, count, cl, clT, cn2);
  pass_xcal <<<512,  256, 0, stream>>>(x, idx, cl, clT, cn2, xcal);
  gemm_out  <<<2048, 256, 0, stream>>>(wb, xcal, fb, out);
}

// Round 7
// 492.843 us; speedup vs baseline: 1.5330x; 1.0839x over previous
//
#include <hip/hip_runtime.h>
#include <stdint.h>

#define B_   8
#define C_   1024
#define HW_  4096
#define K_   64
#define NPIX (B_*HW_)
#define SLAB ((size_t)B_*K_*C_)
#define NSEG 8

typedef __attribute__((ext_vector_type(8))) short short8;
typedef __attribute__((ext_vector_type(4))) float f32x4;

__device__ __forceinline__ uint16_t f2bf(float f) {
  uint32_t u = __float_as_uint(f);
  u += 0x7fffu + ((u >> 16) & 1u);   // round-to-nearest-even
  return (uint16_t)(u >> 16);
}

// async global -> LDS, 16B per lane. LDS dest must be wave-uniform base; lane deposits at base+lane*16.
__device__ __forceinline__ void gl2lds16(const uint16_t* g, uint16_t* l) {
  __builtin_amdgcn_global_load_lds(
      (const __attribute__((address_space(1))) unsigned int*)(g),
      (__attribute__((address_space(3))) unsigned int*)(l), 16, 0, 0);
}

// ---------- prep: normalized centroids, transposed gT[c][n] ----------
__global__ void prep_gT(const float* __restrict__ g, float* __restrict__ gT) {
  int n = blockIdx.x;            // 64 blocks
  int t = threadIdx.x;           // 256 threads
  float vals[4]; float ss = 0.f;
  #pragma unroll
  for (int i = 0; i < 4; i++) { float v = g[n*C_ + t + i*256]; vals[i] = v; ss += v*v; }
  __shared__ float red[256];
  red[t] = ss; __syncthreads();
  for (int s = 128; s > 0; s >>= 1) { if (t < s) red[t] += red[t+s]; __syncthreads(); }
  float scale = 1.f / fmaxf(sqrtf(red[0]), 1e-12f);
  #pragma unroll
  for (int i = 0; i < 4; i++) gT[(t + i*256)*K_ + n] = vals[i]*scale;
}

// ---------- prep: fc_weight fp32 -> bf16 row-major [o][c], 4 elems/thread ----------
__global__ void prep_wb(const float* __restrict__ w, uint16_t* __restrict__ wb) {
  int i = blockIdx.x*256 + threadIdx.x;   // 1024 blocks
  float4 v = *(const float4*)&w[i*4];
  uint16_t o[4] = {f2bf(v.x), f2bf(v.y), f2bf(v.z), f2bf(v.w)};
  *(uint64_t*)&wb[i*4] = *(const uint64_t*)o;
}

// ---------- pass A: argmax_n (x . g_n), fp32, + counts ----------
// R6: de-dup x loads via REGISTER-staged LDS tile (plain ds_write, no
// global_load_lds -- the R5 DMA variant coincided with two container
// failures and is retired). Per 32c x 64px chunk: each thread loads 2
// float4s (issued BEFORE the 512-FMA compute so HBM latency hides under
// it), ds_writes them to the back buffer after compute, one barrier per
// chunk. All 4 waves consume xs[c][lane] (conflict-free broadcast rows).
// Removes the 4x redundant VMEM issue + per-load 64-bit address VALU that
// made R4's VALU issue 2.35x the pure-FMA budget. FMA order over c is
// ascending/unchanged -> bitwise-identical results.
__launch_bounds__(256)
__global__ void pass_assign(const float* __restrict__ x, const float* __restrict__ gT,
                            int* __restrict__ idx, int* __restrict__ count) {
  int bb = blockIdx.x >> 6;      // grid 512 = 8 b * 64 ptiles
  int pt = blockIdx.x & 63;
  int t = threadIdx.x;
  int lane = t & 63;
  int w = t >> 6;
  int ng = __builtin_amdgcn_readfirstlane(w);  // wave id = n-group (uniform -> s_loads of g)
  __shared__ alignas(16) float xs[2][32][64];  // 2 x 8 KB staging
  const float* xb = x + (size_t)bb*C_*HW_ + pt*64;
  const float* gp = gT + ng*16;

  int r0 = t >> 4;               // c-row within chunk for slot t   (0..15)
  int q0 = t & 15;               // float4 group within 64-px row   (0..15)
  const float* p0 = xb + (size_t)r0*HW_ + q0*4;   // slot t      -> xs[.][r0][q0*4]
  const float* p1 = p0 + (size_t)16*HW_;          // slot t+256  -> xs[.][r0+16][q0*4]

  float acc[16];
  #pragma unroll
  for (int n = 0; n < 16; n++) acc[n] = 0.f;

  {
    float4 v0 = *(const float4*)p0;
    float4 v1 = *(const float4*)p1;
    *(float4*)&xs[0][r0][q0*4]    = v0;
    *(float4*)&xs[0][r0+16][q0*4] = v1;
  }
  __syncthreads();               // chunk 0 staged
  for (int cc = 0; cc < 32; cc++) {
    int cur = cc & 1;
    float4 n0, n1;
    if (cc + 1 < 32) {           // issue next chunk's loads; land under the FMAs
      n0 = *(const float4*)(p0 + (size_t)(cc + 1)*32*HW_);
      n1 = *(const float4*)(p1 + (size_t)(cc + 1)*32*HW_);
    }
    #pragma unroll 16
    for (int ci = 0; ci < 32; ci++) {
      float xv = xs[cur][ci][lane];
      const float* gr = gp + (cc*32 + ci)*K_;    // wave-uniform -> s_load
      #pragma unroll
      for (int n2 = 0; n2 < 16; n2++) acc[n2] = fmaf(xv, gr[n2], acc[n2]);
    }
    if (cc + 1 < 32) {           // write-late into the back buffer
      *(float4*)&xs[cur^1][r0][q0*4]    = n0;    // cur^1 last read before the
      *(float4*)&xs[cur^1][r0+16][q0*4] = n1;    // barrier that ended step cc-1
    }
    __syncthreads();             // writes visible; all waves done reading cur
  }

  float best = acc[0]; int bi = 0;
  #pragma unroll
  for (int n = 1; n < 16; n++) { if (acc[n] > best) { best = acc[n]; bi = n; } }
  __shared__ float bv[4][64];
  __shared__ int   bn[4][64];
  __shared__ int   hist[64];
  if (t < 64) hist[t] = 0;
  bv[w][lane] = best; bn[w][lane] = ng*16 + bi;
  __syncthreads();
  if (t < 64) {
    float mv = bv[0][t]; int mn = bn[0][t];
    #pragma unroll
    for (int wv2 = 1; wv2 < 4; wv2++) { if (bv[wv2][t] > mv) { mv = bv[wv2][t]; mn = bn[wv2][t]; } }
    idx[bb*HW_ + pt*64 + t] = mn;
    atomicAdd(&hist[mn], 1);
  }
  __syncthreads();
  if (t < 64 && hist[t] > 0) atomicAdd(&count[bb*K_ + t], hist[t]);
}

// ---------- pass B: sum_x[b,n,c] partials as a one-hot bf16 MFMA GEMM ----------
// D[c][n] = sum_p X[c][p] * onehot[p][n]. No LDS, no atomics.
// grid 1024 = 8 b * 16 ctiles(64 rows) * 8 psegs(512 pixels).
__launch_bounds__(256)
__global__ void pass_bins(const float* __restrict__ x, const int* __restrict__ idx,
                          float* __restrict__ sumxp) {
  int bid = blockIdx.x;
  int ps = bid & 7;              // pixel segment (512 pixels)
  int ct = (bid >> 3) & 15;      // c tile (64 rows)
  int bb = bid >> 7;             // batch
  int t = threadIdx.x;
  int lane = t & 63;
  int w = t >> 6;                // wave -> 16 c-rows
  int col = lane & 15;
  int kg  = lane >> 4;           // k-group: 8 consecutive pixels per lane
  int crow = ct*64 + w*16 + col;
  const float* xp = x + (size_t)bb*C_*HW_ + (size_t)crow*HW_ + ps*512 + kg*8;
  const int*   ip = idx + bb*HW_ + ps*512 + kg*8;

  const f32x4 fzero = {0.f, 0.f, 0.f, 0.f};
  f32x4 acc[4];
  #pragma unroll
  for (int f = 0; f < 4; f++) acc[f] = fzero;

  for (int ks = 0; ks < 16; ks++) {
    // A: 8 consecutive pixels of this c-row, fp32 -> bf16
    float a0[8];
    *(float4*)&a0[0] = *(const float4*)&xp[ks*32];
    *(float4*)&a0[4] = *(const float4*)&xp[ks*32 + 4];
    short8 af;
    #pragma unroll
    for (int j = 0; j < 8; j++) af[j] = (short)f2bf(a0[j]);
    // cluster ids of those 8 pixels (same 32B broadcast across a 16-lane group)
    int iv8[8];
    *(int4*)&iv8[0] = *(const int4*)&ip[ks*32];
    *(int4*)&iv8[4] = *(const int4*)&ip[ks*32 + 4];
    // 4 one-hot B frags cover n = 0..63 (bf16 1.0 = 0x3F80, exact)
    #pragma unroll
    for (int f = 0; f < 4; f++) {
      int n = f*16 + col;
      short8 bfrag;
      #pragma unroll
      for (int j = 0; j < 8; j++) bfrag[j] = (short)((iv8[j] == n) ? 0x3F80 : 0);
      acc[f] = __builtin_amdgcn_mfma_f32_16x16x32_bf16(af, bfrag, acc[f], 0, 0, 0);
    }
  }
  // C/D layout: col = lane&15 (-> n within frag), row = (lane>>4)*4 + reg (-> c-row)
  #pragma unroll
  for (int f = 0; f < 4; f++) {
    int n = f*16 + col;
    size_t base = (size_t)ps*SLAB + ((size_t)bb*K_ + n)*C_ + ct*64 + w*16 + kg*4;
    *(f32x4*)&sumxp[base] = acc[f];   // 16B aligned; lanes of one n fill a 64B line
  }
}

// ---------- pass B2: c_local, c_localT, ||c||^2 (sums the 8 pixel-segment slabs) ----------
__launch_bounds__(256)
__global__ void pass_cfinal(const float* __restrict__ sumxp, const int* __restrict__ count,
                            float* __restrict__ cl, float* __restrict__ clT,
                            float* __restrict__ cn2) {
  int bb = blockIdx.x >> 6, n = blockIdx.x & 63, t = threadIdx.x;  // grid 512
  float inv = 1.f / fmaxf((float)count[bb*K_ + n], 1.f);
  float ss = 0.f;
  #pragma unroll
  for (int i = 0; i < 4; i++) {
    int c = t + i*256;
    size_t o = ((size_t)bb*K_ + n)*C_ + c;
    float v = 0.f;
    #pragma unroll
    for (int s = 0; s < NSEG; s++) v += sumxp[o + (size_t)s*SLAB];
    v *= inv;
    cl [((size_t)bb*K_ + n)*C_ + c] = v;
    clT[((size_t)bb*C_ + c)*K_ + n] = v;
    ss += v*v;
  }
  __shared__ float red[256];
  red[t] = ss; __syncthreads();
  for (int s = 128; s > 0; s >>= 1) { if (t < s) red[t] += red[t+s]; __syncthreads(); }
  if (t == 0) cn2[bb*K_ + n] = red[0];
}

// ---------- pass C0: w[p] then x_cal bf16, transposed [pixel][c] ----------
__launch_bounds__(256)
__global__ void pass_xcal(const float* __restrict__ x, const int* __restrict__ idx,
                          const float* __restrict__ cl, const float* __restrict__ clT,
                          const float* __restrict__ cn2, uint16_t* __restrict__ xcal) {
  int bb = blockIdx.x >> 6, pt = blockIdx.x & 63, t = threadIdx.x;  // grid 512: 64-pixel tiles
  int lane = t & 63, cs = t >> 6;
  __shared__ float xT[64][129];
  __shared__ int   widx[64];
  __shared__ float pdot[4][64], pxsq[4][64], wv[64];
  if (t < 64) widx[t] = idx[bb*HW_ + pt*64 + t];
  __syncthreads();
  const float* xb = x + (size_t)bb*C_*HW_ + pt*64;
  // phase 1: direct per-pixel dot; lane = pixel, wave = c-strip. Coalesced x, 256B clT gather rows.
  int myi = widx[lane];
  const float* clb = clT + (size_t)bb*C_*K_ + myi;
  float dp = 0.f, xq = 0.f;
  #pragma unroll 4
  for (int ci = 0; ci < 256; ci++) {
    int c = cs*256 + ci;
    float xv = xb[(size_t)c*HW_ + lane];
    dp = fmaf(xv, clb[(size_t)c*K_], dp);
    xq = fmaf(xv, xv, xq);
  }
  pdot[cs][lane] = dp; pxsq[cs][lane] = xq;
  __syncthreads();
  if (t < 64) {
    float d = pdot[0][t]+pdot[1][t]+pdot[2][t]+pdot[3][t];
    float q = pxsq[0][t]+pxsq[1][t]+pxsq[2][t]+pxsq[3][t];
    float msd = (q - 2.f*d + cn2[bb*K_ + widx[t]]) * (1.f/1024.f);
    wv[t] = expf(-msd);
  }
  __syncthreads();
  // phase 2: transpose-write bf16 [pixel][c] (x tiles re-read; L2-hot from phase 1)
  for (int cc = 0; cc < 8; cc++) {
    #pragma unroll
    for (int i = 0; i < 32; i++) {
      int co = cs*32 + i;
      xT[lane][co] = xb[(size_t)(cc*128 + co)*HW_ + lane];
    }
    __syncthreads();
    #pragma unroll 2
    for (int pp = 0; pp < 16; pp++) {
      int p = pp*4 + cs;
      float wval = wv[p]; int iv = widx[p];
      const float* clr = cl + ((size_t)bb*K_ + iv)*C_ + cc*128;
      size_t obase = ((size_t)(bb*HW_ + pt*64 + p))*C_ + cc*128;
      #pragma unroll
      for (int ci = 0; ci < 2; ci++) {
        int co = ci*64 + lane;
        float xvv = xT[p][co];
        float v = fmaf(wval, clr[co] - xvv, xvv);   // x + w*(c-x)
        xcal[obase + co] = f2bf(v);
      }
    }
    __syncthreads();
  }
}

// ---------- pass C: out = relu(W @ x_cal + bias), bf16 MFMA, one 128x128 tile/block ----------
// Explicit LDS double-buffer (T3 minimum 2-phase): STAGE(kb+1) issued BEFORE
// the ds_read+MFMA of kb, ONE __syncthreads() per K-step.
#define BK 64
__launch_bounds__(256)
__global__ void gemm_out(const uint16_t* __restrict__ wb, const uint16_t* __restrict__ xcal,
                         const float* __restrict__ bias, float* __restrict__ out) {
  // 64 KB: 2 buffers x (lw 16KB + lx 16KB). Epilogue ep (32 KB) aliases buf0.
  __shared__ alignas(16) uint16_t smem[2*2*128*BK];
  float* ep = (float*)smem;
  int t = threadIdx.x;
  int lane = t & 63;
  int w = t >> 6, wm = w & 1, wn = w >> 1;
  // XCD swizzle: xcd = bid&7; within an XCD, ot fastest -> 8 blocks sharing an xcal
  // tile run consecutively on the SAME XCD (xcal tile + all 8 W tiles stay L2-hot).
  int g  = blockIdx.x & 7;
  int li = blockIdx.x >> 3;
  int ot = li & 7;
  int qt = g*32 + (li >> 3);

  const uint16_t* wsrc = wb   + (size_t)ot*128*C_;
  const uint16_t* xsrc = xcal + (size_t)qt*128*C_;

  const f32x4 fzero = {0.f, 0.f, 0.f, 0.f};
  f32x4 acc[4][4];
  #pragma unroll
  for (int i = 0; i < 4; i++)
    #pragma unroll
    for (int j = 0; j < 4; j++) acc[i][j] = fzero;

  // stage one 128x64 W-tile + 128x64 X-tile into buffer `buf`
  auto STAGE = [&](int buf, int kb) {
    uint16_t* lw = smem + (size_t)buf*2*128*BK;
    uint16_t* lx = lw + 128*BK;
    #pragma unroll
    for (int it = 0; it < 4; it++) {
      int s = t + it*256;              // 1024 slots of 16B per tile
      int r = s >> 3, q = s & 7;
      int qm = q ^ (r & 7);            // inverse swizzle on the global side
      uint16_t* ldw = lw + (size_t)(it*256 + w*64)*8;   // wave-uniform base
      uint16_t* ldx = lx + (size_t)(it*256 + w*64)*8;
      gl2lds16(wsrc + (size_t)r*C_ + kb*BK + qm*8, ldw);
      gl2lds16(xsrc + (size_t)r*C_ + kb*BK + qm*8, ldx);
    }
  };

  STAGE(0, 0);
  __syncthreads();                     // vmcnt(0) drain: buf0 ready
  for (int kb = 0; kb < C_/BK; kb++) {
    int cur = kb & 1;
    if (kb + 1 < C_/BK) STAGE(cur ^ 1, kb + 1);   // loads fly during compute below
    const uint16_t* lw = smem + (size_t)cur*2*128*BK;
    const uint16_t* lx = lw + 128*BK;
    #pragma unroll
    for (int kk = 0; kk < 2; kk++) {
      short8 af[4], bf[4];
      #pragma unroll
      for (int i = 0; i < 4; i++) {
        int row = wm*64 + i*16 + (lane & 15);
        int q = kk*4 + (lane >> 4);
        af[i] = *(const short8*)&lw[row*BK + (q ^ (row & 7))*8];
      }
      #pragma unroll
      for (int j = 0; j < 4; j++) {
        int row = wn*64 + j*16 + (lane & 15);
        int q = kk*4 + (lane >> 4);
        bf[j] = *(const short8*)&lx[row*BK + (q ^ (row & 7))*8];
      }
      #pragma unroll
      for (int i = 0; i < 4; i++)
        #pragma unroll
        for (int j = 0; j < 4; j++)
          acc[i][j] = __builtin_amdgcn_mfma_f32_16x16x32_bf16(af[i], bf[j], acc[i][j], 0, 0, 0);
    }
    __syncthreads();   // drains vmcnt (next buf landed) + all waves done reading cur
  }
  // epilogue: LDS transpose (aliases buf0 -- safe after final barrier) -> float4 row stores
  int col = lane & 15, quad = lane >> 4;
  int bq = (qt*128) >> 12;
  int p0 = (qt*128) & 4095;
  #pragma unroll
  for (int ph = 0; ph < 2; ph++) {
    if (wm == ph) {
      #pragma unroll
      for (int i = 0; i < 4; i++)
        #pragma unroll
        for (int j = 0; j < 4; j++) {
          int p = wn*64 + j*16 + col;
          #pragma unroll
          for (int r = 0; r < 4; r++) {
            int o2 = i*16 + quad*4 + r;   // local o within 64
            ep[o2*128 + (((p >> 2) ^ (o2 & 7)) << 2) + (p & 3)] = acc[i][j][r];
          }
        }
    }
    __syncthreads();
    #pragma unroll
    for (int i2 = 0; i2 < 8; i2++) {
      int s = t + i2*256;
      int ol = s >> 5, pf = s & 31;
      float4 v = *(const float4*)&ep[ol*128 + ((pf ^ (ol & 7)) << 2)];
      int o = ot*128 + ph*64 + ol;
      float bi = bias[o];
      v.x = fmaxf(v.x + bi, 0.f); v.y = fmaxf(v.y + bi, 0.f);
      v.z = fmaxf(v.z + bi, 0.f); v.w = fmaxf(v.w + bi, 0.f);
      *(float4*)&out[(size_t)bq*C_*HW_ + (size_t)o*HW_ + p0 + pf*4] = v;
    }
    __syncthreads();
  }
}

extern "C" void kernel_launch(void* const* d_in, const int* in_sizes, int n_in,
                              void* d_out, int out_size, void* d_ws, size_t ws_size,
                              hipStream_t stream) {
  (void)in_sizes; (void)n_in; (void)out_size; (void)ws_size;
  const float* x    = (const float*)d_in[0];
  const float* cent = (const float*)d_in[1];
  const float* fw   = (const float*)d_in[2];
  const float* fb   = (const float*)d_in[3];
  float* out = (float*)d_out;
  char* ws = (char*)d_ws;
  size_t off = 0;
  float*    gT    = (float*)(ws + off);    off += (size_t)C_*K_*4;        // 256 KB
  int*      idx   = (int*)(ws + off);      off += (size_t)NPIX*4;         // 128 KB
  int*      count = (int*)(ws + off);      off += (size_t)B_*K_*4;        // 2 KB
  float*    sumx  = (float*)(ws + off);    off += (size_t)B_*K_*C_*4;     // 2 MB (unused; keeps offsets identical)
  float*    cl    = (float*)(ws + off);    off += (size_t)B_*K_*C_*4;     // 2 MB
  float*    clT   = (float*)(ws + off);    off += (size_t)B_*C_*K_*4;     // 2 MB
  float*    cn2   = (float*)(ws + off);    off += (size_t)B_*K_*4 + 8;    // 2 KB (+pad->16B)
  uint16_t* wb    = (uint16_t*)(ws + off); off += (size_t)C_*C_*2;        // 2 MB
  uint16_t* xcal  = (uint16_t*)(ws + off); off += (size_t)NPIX*C_*2;     // 64 MB
  (void)sumx;
  // partial-sum slabs (8 x 2 MB) alias the xcal region: dead once pass_cfinal reads them,
  // and pass_xcal only writes xcal afterwards.
  float* sumxp = (float*)xcal;

  hipMemsetAsync(count, 0, (size_t)B_*K_*4, stream);
  prep_gT   <<<64,   256, 0, stream>>>(cent, gT);
  prep_wb   <<<1024, 256, 0, stream>>>(fw, wb);
  pass_assign<<<512, 256, 0, stream>>>(x, gT, idx, count);
  pass_bins <<<1024, 256, 0, stream>>>(x, idx, sumxp);
  pass_cfinal<<<512, 256, 0, stream>>>(sumxp, count, cl, clT, cn2);
  pass_xcal <<<512,  256, 0, stream>>>(x, idx, cl, clT, cn2, xcal);
  gemm_out  <<<2048, 256, 0, stream>>>(wb, xcal, fb, out);
}